// Round 19
// baseline (159.134 us; speedup 1.0000x reference)
//
#include <hip/hip_runtime.h>
#include <hip/hip_bf16.h>

using f32x4 = __attribute__((ext_vector_type(4))) float;
using s16x8 = __attribute__((ext_vector_type(8))) short;

#define MFMA16x16x32(a, b, c) __builtin_amdgcn_mfma_f32_16x16x32_bf16((a), (b), (c), 0, 0, 0)

#define AS_G(p) ((const __attribute__((address_space(1))) void*)(p))
#define AS_L(p) ((__attribute__((address_space(3))) void*)(p))

// barrier with LDS-visibility only: does NOT drain vmcnt
#define BARRIER_LGKM() do { \
    asm volatile("s_waitcnt lgkmcnt(0)" ::: "memory"); \
    __builtin_amdgcn_s_barrier(); \
} while (0)

static __device__ __forceinline__ unsigned short f2bf(float f) {
    unsigned int u = __float_as_uint(f);
    u = (u + 0x7fffu + ((u >> 16) & 1u)) >> 16;
    return (unsigned short)u;
}
static __device__ __forceinline__ unsigned int cvt_pk_bf2(float lo, float hi) {
    unsigned int r;
    asm("v_cvt_pk_bf16_f32 %0, %1, %2" : "=v"(r) : "v"(lo), "v"(hi));
    return r;
}
// swizzled byte offsets — used IDENTICALLY on write and read sides
static __device__ __forceinline__ int swz128(int r, int c) { return (r * 128 + c) ^ ((r & 7) << 4); }
static __device__ __forceinline__ int swz256v(int r, int c) { return (r * 256 + c) ^ ((r & 7) << 4); }

// ---- prologue: weight transposes only (x-cvt fused into QKV GEMM) ----
// blocks [0,1728): w_attn^T; [1728,2304): w_proj^T
__global__ __launch_bounds__(256)
void prologue_kernel(const float* __restrict__ w_attn, unsigned short* __restrict__ wTa,
                     const float* __restrict__ w_proj, unsigned short* __restrict__ wTp) {
    __shared__ float tile[32][33];
    const int bid = blockIdx.x, tid = threadIdx.x;
    const float* w; unsigned short* wt; int K, N, bx, by;
    if (bid < 1728) {
        w = w_attn; wt = wTa; K = 768; N = 2304;
        bx = bid % 72; by = bid / 72;
    } else {
        int id = bid - 1728; w = w_proj; wt = wTp; K = 768; N = 768;
        bx = id % 24; by = id / 24;
    }
    const int tx = tid & 31, ty = tid >> 5;
    const int n0 = bx * 32, k0 = by * 32;
#pragma unroll
    for (int r = 0; r < 4; r++)
        tile[ty * 4 + r][tx] = w[(size_t)(k0 + ty * 4 + r) * N + n0 + tx];
    __syncthreads();
#pragma unroll
    for (int r = 0; r < 4; r++)
        wt[(size_t)(n0 + ty * 4 + r) * K + k0 + tx] = f2bf(tile[tx][ty * 4 + r]);
}

// ---- GEMM: C[M,N] = A[M,K] * Bt[N,K]^T + bias ----
// BK=64 2-phase dbuf, XCD-clustered 1-D grid.
// AF32: A is fp32; staged via regs (8x dwordx4 -> cvt_pk -> 4x ds_write_b128)
// fusing the x->bf16 convert into the GEMM (kills the prologue x pass).
// B always via global_load_lds. vmcnt counted: AF32 -> 12 (8 A + 4 B in
// flight), bf16 -> 8. V-region blocks (n0>=1536) store Vt coalesced via an
// LDS transpose bounce.
template <bool OUT_BF16, bool AF32>
__global__ __launch_bounds__(256, 2)
void gemm_bt(const void* __restrict__ Ain, const unsigned short* __restrict__ Bt,
             const float* __restrict__ bias, void* __restrict__ Cout,
             unsigned short* __restrict__ Vt,
             int M, int N, int K, int ldc, int qcols, float qscale) {
    __shared__ char smem[65536];
    const int tid = threadIdx.x, wid = tid >> 6, lane = tid & 63;
    const int g = lane >> 4, lr = lane & 15;
    const int nx = N >> 7;
    const int ypx = (M >> 7) >> 3;
    const int xcd = blockIdx.x & 7, ii = blockIdx.x >> 3;
    const int m0 = (xcd * ypx + ii / nx) * 128;
    const int n0 = (ii % nx) * 128;
    const int wm = wid >> 1, wn = wid & 1;

    f32x4 acc[4][4];
#pragma unroll
    for (int i = 0; i < 4; i++)
#pragma unroll
        for (int j = 0; j < 4; j++) acc[i][j] = f32x4{0.f, 0.f, 0.f, 0.f};

    const int rbase = lane >> 3;
    const int cSw = ((lane & 7) << 4) ^ (rbase << 4);

    // B staging: 4 gload_lds per thread into B-half [16K,32K)
    auto STAGE_B = [&](int buf, int kt) {
        char* base = smem + buf * 32768 + 16384;
#pragma unroll
        for (int ww = 0; ww < 4; ww++) {
            int w = wid * 4 + ww;
            int r = w * 8 + rbase;
            const unsigned short* srcB = Bt + (size_t)(n0 + r) * K + kt + (cSw >> 1);
            __builtin_amdgcn_global_load_lds(AS_G(srcB), AS_L(base + w * 1024), 16, 0, 0);
        }
    };

    const int nk = K >> 6;

    if constexpr (AF32) {
        const float* Af = (const float*)Ain;
        const int ar = tid >> 1;            // A row this thread stages
        const int ach = tid & 1;            // col-half (32 f32 elements)
        const float* aSrc = Af + (size_t)(m0 + ar) * K + ach * 32;

        float4 areg[8];
        auto LOAD_A = [&](int kt) {
#pragma unroll
            for (int i = 0; i < 8; i++)
                areg[i] = *(const float4*)(aSrc + kt + i * 4);
        };
        auto WRITE_A = [&](int buf) {
            char* base = smem + buf * 32768;
#pragma unroll
            for (int i = 0; i < 4; i++) {
                uint4 dw;
                dw.x = cvt_pk_bf2(areg[2 * i].x, areg[2 * i].y);
                dw.y = cvt_pk_bf2(areg[2 * i].z, areg[2 * i].w);
                dw.z = cvt_pk_bf2(areg[2 * i + 1].x, areg[2 * i + 1].y);
                dw.w = cvt_pk_bf2(areg[2 * i + 1].z, areg[2 * i + 1].w);
                *(uint4*)(base + swz128(ar, ach * 64 + i * 16)) = dw;
            }
        };

        LOAD_A(0);
        STAGE_B(0, 0);
        WRITE_A(0);

        for (int t = 0; t < nk; t++) {
            if (t + 1 < nk) {
                LOAD_A((t + 1) << 6);
                STAGE_B((t + 1) & 1, (t + 1) << 6);
                asm volatile("s_waitcnt vmcnt(12)" ::: "memory"); // B(t) landed
            } else {
                asm volatile("s_waitcnt vmcnt(0)" ::: "memory");
            }
            asm volatile("s_waitcnt lgkmcnt(0)" ::: "memory");    // A writes visible
            __builtin_amdgcn_s_barrier();
            char* cbase = smem + (t & 1) * 32768;
#pragma unroll
            for (int ks = 0; ks < 2; ks++) {
                s16x8 af[4], bfr[4];
#pragma unroll
                for (int i = 0; i < 4; i++)
                    af[i] = *(const s16x8*)(cbase + swz128(wm * 64 + i * 16 + lr, ks * 64 + g * 16));
#pragma unroll
                for (int j = 0; j < 4; j++)
                    bfr[j] = *(const s16x8*)(cbase + 16384 + swz128(wn * 64 + j * 16 + lr, ks * 64 + g * 16));
#pragma unroll
                for (int i = 0; i < 4; i++)
#pragma unroll
                    for (int j = 0; j < 4; j++)
                        acc[i][j] = MFMA16x16x32(af[i], bfr[j], acc[i][j]);
            }
            if (t + 1 < nk) WRITE_A((t + 1) & 1);   // other buffer; race-free
            BARRIER_LGKM();
        }
    } else {
        const unsigned short* Ab = (const unsigned short*)Ain;
        auto STAGE_A = [&](int buf, int kt) {
            char* base = smem + buf * 32768;
#pragma unroll
            for (int ww = 0; ww < 4; ww++) {
                int w = wid * 4 + ww;
                int r = w * 8 + rbase;
                const unsigned short* srcA = Ab + (size_t)(m0 + r) * K + kt + (cSw >> 1);
                __builtin_amdgcn_global_load_lds(AS_G(srcA), AS_L(base + w * 1024), 16, 0, 0);
            }
        };

        STAGE_A(0, 0);
        STAGE_B(0, 0);

        for (int t = 0; t < nk; t++) {
            if (t + 1 < nk) {
                STAGE_A((t + 1) & 1, (t + 1) << 6);
                STAGE_B((t + 1) & 1, (t + 1) << 6);
                asm volatile("s_waitcnt vmcnt(8)" ::: "memory");
            } else {
                asm volatile("s_waitcnt vmcnt(0)" ::: "memory");
            }
            __builtin_amdgcn_s_barrier();
            char* cbase = smem + (t & 1) * 32768;
#pragma unroll
            for (int ks = 0; ks < 2; ks++) {
                s16x8 af[4], bfr[4];
#pragma unroll
                for (int i = 0; i < 4; i++)
                    af[i] = *(const s16x8*)(cbase + swz128(wm * 64 + i * 16 + lr, ks * 64 + g * 16));
#pragma unroll
                for (int j = 0; j < 4; j++)
                    bfr[j] = *(const s16x8*)(cbase + 16384 + swz128(wn * 64 + j * 16 + lr, ks * 64 + g * 16));
#pragma unroll
                for (int i = 0; i < 4; i++)
#pragma unroll
                    for (int j = 0; j < 4; j++)
                        acc[i][j] = MFMA16x16x32(af[i], bfr[j], acc[i][j]);
            }
            BARRIER_LGKM();
        }
    }

    if (Vt != nullptr && n0 >= 1536) {
        // V block: bounce C-tile through LDS transposed, store coalesced.
#pragma unroll
        for (int j = 0; j < 4; j++) {
            int dl = wn * 64 + j * 16 + lr;
            float bv = bias[n0 + dl];
#pragma unroll
            for (int i = 0; i < 4; i++) {
                int tl = wm * 64 + i * 16 + g * 4;
                ushort4 o4;
                o4.x = f2bf(acc[i][j][0] + bv);
                o4.y = f2bf(acc[i][j][1] + bv);
                o4.z = f2bf(acc[i][j][2] + bv);
                o4.w = f2bf(acc[i][j][3] + bv);
                *(ushort4*)(smem + swz256v(dl, tl * 2)) = o4;
            }
        }
        __syncthreads();
        const int bb = m0 >> 11, t0 = m0 & 2047;
#pragma unroll
        for (int it = 0; it < 8; it++) {
            int dl = it * 16 + wid * 4 + g;
            int dg = (n0 - 1536) + dl;
            int hh = dg >> 6, dd = dg & 63;
            s16x8 v = *(const s16x8*)(smem + swz256v(dl, lr * 16));
            *(s16x8*)(Vt + ((((size_t)bb * 12 + hh) * 64 + dd) << 11) + t0 + lr * 8) = v;
        }
    } else {
#pragma unroll
        for (int j = 0; j < 4; j++) {
            int c = n0 + wn * 64 + j * 16 + lr;
            float bv = bias[c];
            float cscale = (c < qcols) ? qscale : 1.0f;
#pragma unroll
            for (int i = 0; i < 4; i++) {
#pragma unroll
                for (int rg = 0; rg < 4; rg++) {
                    int r = m0 + wm * 64 + i * 16 + g * 4 + rg;
                    float val = (acc[i][j][rg] + bv) * cscale;
                    if constexpr (OUT_BF16)
                        ((unsigned short*)Cout)[(size_t)r * ldc + c] = f2bf(val);
                    else
                        ((float*)Cout)[(size_t)r * ldc + c] = val;
                }
            }
        }
    }
}

// ---- causal flash attention: EXACT round-14 body (best: 49.4 us) ----
__global__ __launch_bounds__(256, 2)
void attn_kernel(const unsigned short* __restrict__ qk, const unsigned short* __restrict__ Vt,
                 unsigned short* __restrict__ y) {
    __shared__ char smem[49152];
    const int tid = threadIdx.x, wid = tid >> 6, lane = tid & 63;
    const int g = lane >> 4, lr = lane & 15;
    const int T = 2048;

    const int s = blockIdx.x;
    const int xcd = s & 7, i = s >> 3;
    const int grp = xcd * 6 + (i >> 4);
    const int qpi = i & 15;
    const int h = grp % 12, b = grp / 12;
    const int qtA = qpi, qtB = 31 - qpi;
    const int q0A = qtA * 64, q0B = qtB * 64;

    const int krow = tid >> 2;
    const int kcol = (tid & 3) * 32;

    s16x8 vone;
#pragma unroll
    for (int e = 0; e < 8; e++) vone[e] = (short)0x3F80;   // bf16 1.0

    const unsigned short* qrowA = qk + (size_t)(b * T + q0A + wid * 16 + lr) * 1536 + h * 64;
    const unsigned short* qrowB = qk + (size_t)(b * T + q0B + wid * 16 + lr) * 1536 + h * 64;
    s16x8 aqA[2], aqB[2];
    aqA[0] = *(const s16x8*)(qrowA + g * 8);
    aqA[1] = *(const s16x8*)(qrowA + 32 + g * 8);
    aqB[0] = *(const s16x8*)(qrowB + g * 8);
    aqB[1] = *(const s16x8*)(qrowB + 32 + g * 8);

    f32x4 oA[4], oB[4], lsumA, lsumB;
#pragma unroll
    for (int r = 0; r < 4; r++) { oA[r] = f32x4{0.f, 0.f, 0.f, 0.f}; oB[r] = f32x4{0.f, 0.f, 0.f, 0.f}; }
    lsumA = f32x4{0.f, 0.f, 0.f, 0.f};
    lsumB = f32x4{0.f, 0.f, 0.f, 0.f};

    const unsigned short* pkBase = qk + (size_t)(b * T + krow) * 1536 + 768 + h * 64 + (kcol >> 1);
    const unsigned short* pvBase = Vt + ((((size_t)b * 12 + h) * 64 + krow) << 11) + (kcol >> 1);

    const int ntA = qtA + 1, ntB = qtB + 1;

    // prologue: load tile 0 -> buf0; issue loads for tile 1
    s16x8 k0 = *(const s16x8*)(pkBase);
    s16x8 k1 = *(const s16x8*)(pkBase + 8);
    s16x8 v0 = *(const s16x8*)(pvBase);
    s16x8 v1 = *(const s16x8*)(pvBase + 8);
    *(s16x8*)(smem + swz128(krow, kcol)) = k0;
    *(s16x8*)(smem + swz128(krow, kcol + 16)) = k1;
    *(s16x8*)(smem + 16384 + swz128(krow, kcol)) = v0;
    *(s16x8*)(smem + 16384 + swz128(krow, kcol + 16)) = v1;
    if (ntB > 1) {
        const unsigned short* pk = pkBase + (size_t)64 * 1536;
        k0 = *(const s16x8*)(pk);
        k1 = *(const s16x8*)(pk + 8);
        const unsigned short* pv = pvBase + 64;
        v0 = *(const s16x8*)(pv);
        v1 = *(const s16x8*)(pv + 8);
    }
    BARRIER_LGKM();

    char* const pbaseB = smem + 32768 + wid * 2048;
    char* const pbaseA = smem + 40960 + wid * 2048;
    const int q_rel = wid * 16 + lr;

    for (int t = 0; t < ntB; t++) {
        char* kbase = smem + (t & 1) * 8192;
        char* vbase = smem + 16384 + (t & 1) * 8192;
        const bool actA = (t < ntA);

        // ---- phase 1: QK^T + exp + P-write for B, then A (separate buffers) ----
        {
            f32x4 st[4];
            __builtin_amdgcn_s_setprio(1);
#pragma unroll
            for (int nf = 0; nf < 4; nf++) {
                f32x4 sf = f32x4{0.f, 0.f, 0.f, 0.f};
#pragma unroll
                for (int ks = 0; ks < 2; ks++) {
                    s16x8 ak = *(const s16x8*)(kbase + swz128(nf * 16 + lr, (ks * 32 + g * 8) * 2));
                    sf = MFMA16x16x32(ak, aqB[ks], sf);
                }
                st[nf] = sf;
            }
            __builtin_amdgcn_s_setprio(0);
            const bool diag = (t == ntB - 1);
#pragma unroll
            for (int nf = 0; nf < 4; nf++)
#pragma unroll
                for (int rg = 0; rg < 4; rg++) {
                    float p = __builtin_amdgcn_exp2f(st[nf][rg]);
                    if (diag && (nf * 16 + g * 4 + rg > q_rel)) p = 0.f;
                    st[nf][rg] = p;
                }
#pragma unroll
            for (int nf = 0; nf < 4; nf++) {
                uint2 dw;
                dw.x = cvt_pk_bf2(st[nf][0], st[nf][1]);
                dw.y = cvt_pk_bf2(st[nf][2], st[nf][3]);
                *(uint2*)(pbaseB + swz128(lr, nf * 32 + g * 8)) = dw;
            }
        }
        if (actA) {
            f32x4 st[4];
            __builtin_amdgcn_s_setprio(1);
#pragma unroll
            for (int nf = 0; nf < 4; nf++) {
                f32x4 sf = f32x4{0.f, 0.f, 0.f, 0.f};
#pragma unroll
                for (int ks = 0; ks < 2; ks++) {
                    s16x8 ak = *(const s16x8*)(kbase + swz128(nf * 16 + lr, (ks * 32 + g * 8) * 2));
                    sf = MFMA16x16x32(ak, aqA[ks], sf);
                }
                st[nf] = sf;
            }
            __builtin_amdgcn_s_setprio(0);
            const bool diag = (t == ntA - 1);
#pragma unroll
            for (int nf = 0; nf < 4; nf++)
#pragma unroll
                for (int rg = 0; rg < 4; rg++) {
                    float p = __builtin_amdgcn_exp2f(st[nf][rg]);
                    if (diag && (nf * 16 + g * 4 + rg > q_rel)) p = 0.f;
                    st[nf][rg] = p;
                }
#pragma unroll
            for (int nf = 0; nf < 4; nf++) {
                uint2 dw;
                dw.x = cvt_pk_bf2(st[nf][0], st[nf][1]);
                dw.y = cvt_pk_bf2(st[nf][2], st[nf][3]);
                *(uint2*)(pbaseA + swz128(lr, nf * 32 + g * 8)) = dw;
            }
        }

        // ---- phase 2: P-read + PV + ones-MFMA row-sum for B, then A ----
        {
            s16x8 pf[2];
#pragma unroll
            for (int ks = 0; ks < 2; ks++)
                pf[ks] = *(const s16x8*)(pbaseB + swz128(lr, ks * 64 + g * 16));
            __builtin_amdgcn_s_setprio(1);
#pragma unroll
            for (int nf = 0; nf < 4; nf++) {
#pragma unroll
                for (int ks = 0; ks < 2; ks++) {
                    s16x8 bv = *(const s16x8*)(vbase + swz128(nf * 16 + lr, ks * 64 + g * 16));
                    oB[nf] = MFMA16x16x32(pf[ks], bv, oB[nf]);
                }
            }
            lsumB = MFMA16x16x32(pf[0], vone, lsumB);
            lsumB = MFMA16x16x32(pf[1], vone, lsumB);
            __builtin_amdgcn_s_setprio(0);
        }
        if (actA) {
            s16x8 pf[2];
#pragma unroll
            for (int ks = 0; ks < 2; ks++)
                pf[ks] = *(const s16x8*)(pbaseA + swz128(lr, ks * 64 + g * 16));
            __builtin_amdgcn_s_setprio(1);
#pragma unroll
            for (int nf = 0; nf < 4; nf++) {
#pragma unroll
                for (int ks = 0; ks < 2; ks++) {
                    s16x8 bv = *(const s16x8*)(vbase + swz128(nf * 16 + lr, ks * 64 + g * 16));
                    oA[nf] = MFMA16x16x32(pf[ks], bv, oA[nf]);
                }
            }
            lsumA = MFMA16x16x32(pf[0], vone, lsumA);
            lsumA = MFMA16x16x32(pf[1], vone, lsumA);
            __builtin_amdgcn_s_setprio(0);
        }

        // stage tile t+1 into the other buffer; issue loads for t+2
        if (t + 1 < ntB) {
            char* kn = smem + ((t + 1) & 1) * 8192;
            char* vn = smem + 16384 + ((t + 1) & 1) * 8192;
            *(s16x8*)(kn + swz128(krow, kcol)) = k0;
            *(s16x8*)(kn + swz128(krow, kcol + 16)) = k1;
            *(s16x8*)(vn + swz128(krow, kcol)) = v0;
            *(s16x8*)(vn + swz128(krow, kcol + 16)) = v1;
            if (t + 2 < ntB) {
                const unsigned short* pk = pkBase + (size_t)(t + 2) * 64 * 1536;
                k0 = *(const s16x8*)(pk);
                k1 = *(const s16x8*)(pk + 8);
                const unsigned short* pv = pvBase + (t + 2) * 64;
                v0 = *(const s16x8*)(pv);
                v1 = *(const s16x8*)(pv + 8);
            }
        }
        BARRIER_LGKM();              // single barrier per tile
    }

    // epilogue: lsum[rg] is the row-sum for q = wid*16+g*4+rg — same slot as o
#pragma unroll
    for (int which = 0; which < 2; which++) {
        const f32x4 lsum = which ? lsumB : lsumA;
        const int q0 = which ? q0B : q0A;
        f32x4* o = which ? oB : oA;
        float linv_q[4];
#pragma unroll
        for (int rg = 0; rg < 4; rg++) linv_q[rg] = 1.0f / lsum[rg];
#pragma unroll
        for (int nf = 0; nf < 4; nf++) {
#pragma unroll
            for (int rg = 0; rg < 4; rg++) {
                int row = b * T + q0 + wid * 16 + g * 4 + rg;
                int col = h * 64 + nf * 16 + lr;
                y[(size_t)row * 768 + col] = f2bf(o[nf][rg] * linv_q[rg]);
            }
        }
    }
}

extern "C" void kernel_launch(void* const* d_in, const int* in_sizes, int n_in,
                              void* d_out, int out_size, void* d_ws, size_t ws_size,
                              hipStream_t stream) {
    const float* x      = (const float*)d_in[0];
    const float* w_attn = (const float*)d_in[1];
    const float* b_attn = (const float*)d_in[2];
    const float* w_proj = (const float*)d_in[3];
    const float* b_proj = (const float*)d_in[4];

    char* ws = (char*)d_ws;
    unsigned short* qk  = (unsigned short*)(ws);
    unsigned short* Vt  = (unsigned short*)(ws + 25165824);
    unsigned short* wTa = (unsigned short*)(ws + 37748736);
    unsigned short* wTp = (unsigned short*)(ws + 41287680);

    const bool big = ws_size >= (size_t)55050240;
    unsigned short* yb = big ? (unsigned short*)(ws + 42467328)
                             : (unsigned short*)d_out;   // d_out dead until proj
    float* projOut = big ? (float*)d_out : (float*)ws;

    prologue_kernel<<<2304, 256, 0, stream>>>(w_attn, wTa, w_proj, wTp);

    // qscale = 0.125 * log2(e): softmax scale and exp->exp2 folded into Q.
    // A = x (fp32) staged+converted inside the GEMM.
    gemm_bt<true, true><<<1152, 256, 0, stream>>>((const void*)x, wTa, b_attn, (void*)qk, Vt,
                                                  8192, 2304, 768, 1536, 768, 0.1803368801111244f);
    attn_kernel<<<768, 256, 0, stream>>>(qk, Vt, yb);
    gemm_bt<false, false><<<384, 256, 0, stream>>>((const void*)yb, wTp, b_proj, (void*)projOut, nullptr,
                                                   8192, 768, 768, 768, 0, 1.0f);
    if (!big)
        hipMemcpyAsync(d_out, projOut, 25165824, hipMemcpyDeviceToDevice, stream);
}

// Round 20
// 116.873 us; speedup vs baseline: 1.3616x; 1.3616x over previous
//
#include <hip/hip_runtime.h>
#include <hip/hip_bf16.h>

using f32x4 = __attribute__((ext_vector_type(4))) float;
using s16x8 = __attribute__((ext_vector_type(8))) short;

#define MFMA16x16x32(a, b, c) __builtin_amdgcn_mfma_f32_16x16x32_bf16((a), (b), (c), 0, 0, 0)

#define AS_G(p) ((const __attribute__((address_space(1))) void*)(p))
#define AS_L(p) ((__attribute__((address_space(3))) void*)(p))

// barrier with LDS-visibility only: does NOT drain vmcnt
#define BARRIER_LGKM() do { \
    asm volatile("s_waitcnt lgkmcnt(0)" ::: "memory"); \
    __builtin_amdgcn_s_barrier(); \
} while (0)

static __device__ __forceinline__ unsigned short f2bf(float f) {
    unsigned int u = __float_as_uint(f);
    u = (u + 0x7fffu + ((u >> 16) & 1u)) >> 16;
    return (unsigned short)u;
}
static __device__ __forceinline__ unsigned int cvt_pk_bf2(float lo, float hi) {
    unsigned int r;
    asm("v_cvt_pk_bf16_f32 %0, %1, %2" : "=v"(r) : "v"(lo), "v"(hi));
    return r;
}
// swizzled byte offsets — used IDENTICALLY on write and read sides
static __device__ __forceinline__ int swz128(int r, int c) { return (r * 128 + c) ^ ((r & 7) << 4); }
static __device__ __forceinline__ int swz256v(int r, int c) { return (r * 256 + c) ^ ((r & 7) << 4); }

// ---- fused prologue: x->bf16 convert + both weight transposes ----
__global__ __launch_bounds__(256)
void prologue_kernel(const float* __restrict__ x, unsigned short* __restrict__ xb,
                     const float* __restrict__ w_attn, unsigned short* __restrict__ wTa,
                     const float* __restrict__ w_proj, unsigned short* __restrict__ wTp) {
    __shared__ float tile[32][33];
    const int bid = blockIdx.x, tid = threadIdx.x;
    if (bid < 2048) {
        const int n = 8192 * 768;
        int i = (bid * 256 + tid) * 4;
        const int stride = 2048 * 256 * 4;
        for (; i < n; i += stride) {
            float4 v = *(const float4*)(x + i);
            ushort4 o;
            o.x = f2bf(v.x); o.y = f2bf(v.y); o.z = f2bf(v.z); o.w = f2bf(v.w);
            *(ushort4*)(xb + i) = o;
        }
    } else {
        const float* w; unsigned short* wt; int K, N, bx, by;
        if (bid < 3776) {
            int id = bid - 2048; w = w_attn; wt = wTa; K = 768; N = 2304;
            bx = id % 72; by = id / 72;
        } else {
            int id = bid - 3776; w = w_proj; wt = wTp; K = 768; N = 768;
            bx = id % 24; by = id / 24;
        }
        const int tx = tid & 31, ty = tid >> 5;
        const int n0 = bx * 32, k0 = by * 32;
#pragma unroll
        for (int r = 0; r < 4; r++)
            tile[ty * 4 + r][tx] = w[(size_t)(k0 + ty * 4 + r) * N + n0 + tx];
        __syncthreads();
#pragma unroll
        for (int r = 0; r < 4; r++)
            wt[(size_t)(n0 + ty * 4 + r) * K + k0 + tx] = f2bf(tile[tx][ty * 4 + r]);
    }
}

// ---- GEMM: C[M,N] = A[M,K] * Bt[N,K]^T + bias (round-18 proven) ----
// BK=64 2-phase dbuf gload_lds, XCD-clustered 1-D grid, counted vmcnt(8).
// V-region blocks (n0>=1536) store Vt coalesced via LDS transpose bounce.
template <bool OUT_BF16>
__global__ __launch_bounds__(256, 2)
void gemm_bt(const unsigned short* __restrict__ A, const unsigned short* __restrict__ Bt,
             const float* __restrict__ bias, void* __restrict__ Cout,
             unsigned short* __restrict__ Vt,
             int M, int N, int K, int ldc, int qcols, float qscale) {
    __shared__ char smem[65536];
    const int tid = threadIdx.x, wid = tid >> 6, lane = tid & 63;
    const int g = lane >> 4, lr = lane & 15;
    const int nx = N >> 7;
    const int ypx = (M >> 7) >> 3;
    const int xcd = blockIdx.x & 7, ii = blockIdx.x >> 3;
    const int m0 = (xcd * ypx + ii / nx) * 128;
    const int n0 = (ii % nx) * 128;
    const int wm = wid >> 1, wn = wid & 1;

    f32x4 acc[4][4];
#pragma unroll
    for (int i = 0; i < 4; i++)
#pragma unroll
        for (int j = 0; j < 4; j++) acc[i][j] = f32x4{0.f, 0.f, 0.f, 0.f};

    const int rbase = lane >> 3;
    const int cSw = ((lane & 7) << 4) ^ (rbase << 4);

    auto STAGE = [&](int buf, int kt) {
        char* base = smem + buf * 32768;
#pragma unroll
        for (int ww = 0; ww < 4; ww++) {
            int w = wid * 4 + ww;
            int r = w * 8 + rbase;
            const unsigned short* srcA = A + (size_t)(m0 + r) * K + kt + (cSw >> 1);
            __builtin_amdgcn_global_load_lds(AS_G(srcA), AS_L(base + w * 1024), 16, 0, 0);
            const unsigned short* srcB = Bt + (size_t)(n0 + r) * K + kt + (cSw >> 1);
            __builtin_amdgcn_global_load_lds(AS_G(srcB), AS_L(base + 16384 + w * 1024), 16, 0, 0);
        }
    };

    const int nk = K >> 6;
    STAGE(0, 0);

    for (int t = 0; t < nk; t++) {
        if (t + 1 < nk) {
            STAGE((t + 1) & 1, (t + 1) << 6);
            asm volatile("s_waitcnt vmcnt(8)" ::: "memory");   // t's 8 loads done
        } else {
            asm volatile("s_waitcnt vmcnt(0)" ::: "memory");
        }
        __builtin_amdgcn_s_barrier();
        char* cbase = smem + (t & 1) * 32768;
#pragma unroll
        for (int ks = 0; ks < 2; ks++) {
            s16x8 af[4], bfr[4];
#pragma unroll
            for (int i = 0; i < 4; i++)
                af[i] = *(const s16x8*)(cbase + swz128(wm * 64 + i * 16 + lr, ks * 64 + g * 16));
#pragma unroll
            for (int j = 0; j < 4; j++)
                bfr[j] = *(const s16x8*)(cbase + 16384 + swz128(wn * 64 + j * 16 + lr, ks * 64 + g * 16));
#pragma unroll
            for (int i = 0; i < 4; i++)
#pragma unroll
                for (int j = 0; j < 4; j++)
                    acc[i][j] = MFMA16x16x32(af[i], bfr[j], acc[i][j]);
        }
        BARRIER_LGKM();
    }

    if (Vt != nullptr && n0 >= 1536) {
        // V block: bounce C-tile through LDS transposed, store coalesced.
#pragma unroll
        for (int j = 0; j < 4; j++) {
            int dl = wn * 64 + j * 16 + lr;
            float bv = bias[n0 + dl];
#pragma unroll
            for (int i = 0; i < 4; i++) {
                int tl = wm * 64 + i * 16 + g * 4;
                ushort4 o4;
                o4.x = f2bf(acc[i][j][0] + bv);
                o4.y = f2bf(acc[i][j][1] + bv);
                o4.z = f2bf(acc[i][j][2] + bv);
                o4.w = f2bf(acc[i][j][3] + bv);
                *(ushort4*)(smem + swz256v(dl, tl * 2)) = o4;
            }
        }
        __syncthreads();
        const int bb = m0 >> 11, t0 = m0 & 2047;
#pragma unroll
        for (int it = 0; it < 8; it++) {
            int dl = it * 16 + wid * 4 + g;
            int dg = (n0 - 1536) + dl;
            int hh = dg >> 6, dd = dg & 63;
            s16x8 v = *(const s16x8*)(smem + swz256v(dl, lr * 16));
            *(s16x8*)(Vt + ((((size_t)bb * 12 + hh) * 64 + dd) << 11) + t0 + lr * 8) = v;
        }
    } else {
#pragma unroll
        for (int j = 0; j < 4; j++) {
            int c = n0 + wn * 64 + j * 16 + lr;
            float bv = bias[c];
            float cscale = (c < qcols) ? qscale : 1.0f;
#pragma unroll
            for (int i = 0; i < 4; i++) {
#pragma unroll
                for (int rg = 0; rg < 4; rg++) {
                    int r = m0 + wm * 64 + i * 16 + g * 4 + rg;
                    float val = (acc[i][j][rg] + bv) * cscale;
                    if constexpr (OUT_BF16)
                        ((unsigned short*)Cout)[(size_t)r * ldc + c] = f2bf(val);
                    else
                        ((float*)Cout)[(size_t)r * ldc + c] = val;
                }
            }
        }
    }
}

// ---- proj GEMM, BM=64 variant: fixes 1.5 blocks/CU imbalance (384 -> 768
// blocks = exactly 3/CU). 64x128 tile, 4 waves 1x4 (each 64 rows x 32 cols,
// acc[4][2]); LDS 2 x (A 8K + B 16K) = 48KB -> 3 blocks/CU. Same staging
// pattern, counted vmcnt(6). fp32 output + bias (proj epilogue only).
__global__ __launch_bounds__(256, 3)
void gemm_bt_half(const unsigned short* __restrict__ A, const unsigned short* __restrict__ Bt,
                  const float* __restrict__ bias, float* __restrict__ Cout,
                  int M, int N, int K, int ldc) {
    __shared__ char smem[49152];
    const int tid = threadIdx.x, wid = tid >> 6, lane = tid & 63;
    const int g = lane >> 4, lr = lane & 15;
    const int nx = N >> 7;
    const int ypx = (M >> 6) >> 3;           // 64-row tiles per XCD
    const int xcd = blockIdx.x & 7, ii = blockIdx.x >> 3;
    const int m0 = (xcd * ypx + ii / nx) * 64;
    const int n0 = (ii % nx) * 128;

    f32x4 acc[4][2];
#pragma unroll
    for (int i = 0; i < 4; i++)
#pragma unroll
        for (int j = 0; j < 2; j++) acc[i][j] = f32x4{0.f, 0.f, 0.f, 0.f};

    const int rbase = lane >> 3;
    const int cSw = ((lane & 7) << 4) ^ (rbase << 4);

    auto STAGE = [&](int buf, int kt) {
        char* base = smem + buf * 24576;
        // A: 64 rows (2 issues/thread)
#pragma unroll
        for (int ww = 0; ww < 2; ww++) {
            int w = wid * 2 + ww;            // 0..7
            int r = w * 8 + rbase;
            const unsigned short* srcA = A + (size_t)(m0 + r) * K + kt + (cSw >> 1);
            __builtin_amdgcn_global_load_lds(AS_G(srcA), AS_L(base + w * 1024), 16, 0, 0);
        }
        // B: 128 rows (4 issues/thread)
#pragma unroll
        for (int ww = 0; ww < 4; ww++) {
            int w = wid * 4 + ww;            // 0..15
            int r = w * 8 + rbase;
            const unsigned short* srcB = Bt + (size_t)(n0 + r) * K + kt + (cSw >> 1);
            __builtin_amdgcn_global_load_lds(AS_G(srcB), AS_L(base + 8192 + w * 1024), 16, 0, 0);
        }
    };

    const int nk = K >> 6;
    STAGE(0, 0);

    for (int t = 0; t < nk; t++) {
        if (t + 1 < nk) {
            STAGE((t + 1) & 1, (t + 1) << 6);
            asm volatile("s_waitcnt vmcnt(6)" ::: "memory");   // t's 6 loads done
        } else {
            asm volatile("s_waitcnt vmcnt(0)" ::: "memory");
        }
        __builtin_amdgcn_s_barrier();
        char* cbase = smem + (t & 1) * 24576;
#pragma unroll
        for (int ks = 0; ks < 2; ks++) {
            s16x8 af[4], bfr[2];
#pragma unroll
            for (int i = 0; i < 4; i++)
                af[i] = *(const s16x8*)(cbase + swz128(i * 16 + lr, ks * 64 + g * 16));
#pragma unroll
            for (int j = 0; j < 2; j++)
                bfr[j] = *(const s16x8*)(cbase + 8192 + swz128(wid * 32 + j * 16 + lr, ks * 64 + g * 16));
#pragma unroll
            for (int i = 0; i < 4; i++)
#pragma unroll
                for (int j = 0; j < 2; j++)
                    acc[i][j] = MFMA16x16x32(af[i], bfr[j], acc[i][j]);
        }
        BARRIER_LGKM();
    }

#pragma unroll
    for (int j = 0; j < 2; j++) {
        int c = n0 + wid * 32 + j * 16 + lr;
        float bv = bias[c];
#pragma unroll
        for (int i = 0; i < 4; i++) {
#pragma unroll
            for (int rg = 0; rg < 4; rg++) {
                int r = m0 + i * 16 + g * 4 + rg;
                Cout[(size_t)r * ldc + c] = acc[i][j][rg] + bv;
            }
        }
    }
}

// ---- causal flash attention: EXACT round-14 body (best: 49.4 us) ----
__global__ __launch_bounds__(256, 2)
void attn_kernel(const unsigned short* __restrict__ qk, const unsigned short* __restrict__ Vt,
                 unsigned short* __restrict__ y) {
    __shared__ char smem[49152];
    const int tid = threadIdx.x, wid = tid >> 6, lane = tid & 63;
    const int g = lane >> 4, lr = lane & 15;
    const int T = 2048;

    const int s = blockIdx.x;
    const int xcd = s & 7, i = s >> 3;
    const int grp = xcd * 6 + (i >> 4);
    const int qpi = i & 15;
    const int h = grp % 12, b = grp / 12;
    const int qtA = qpi, qtB = 31 - qpi;
    const int q0A = qtA * 64, q0B = qtB * 64;

    const int krow = tid >> 2;
    const int kcol = (tid & 3) * 32;

    s16x8 vone;
#pragma unroll
    for (int e = 0; e < 8; e++) vone[e] = (short)0x3F80;   // bf16 1.0

    const unsigned short* qrowA = qk + (size_t)(b * T + q0A + wid * 16 + lr) * 1536 + h * 64;
    const unsigned short* qrowB = qk + (size_t)(b * T + q0B + wid * 16 + lr) * 1536 + h * 64;
    s16x8 aqA[2], aqB[2];
    aqA[0] = *(const s16x8*)(qrowA + g * 8);
    aqA[1] = *(const s16x8*)(qrowA + 32 + g * 8);
    aqB[0] = *(const s16x8*)(qrowB + g * 8);
    aqB[1] = *(const s16x8*)(qrowB + 32 + g * 8);

    f32x4 oA[4], oB[4], lsumA, lsumB;
#pragma unroll
    for (int r = 0; r < 4; r++) { oA[r] = f32x4{0.f, 0.f, 0.f, 0.f}; oB[r] = f32x4{0.f, 0.f, 0.f, 0.f}; }
    lsumA = f32x4{0.f, 0.f, 0.f, 0.f};
    lsumB = f32x4{0.f, 0.f, 0.f, 0.f};

    const unsigned short* pkBase = qk + (size_t)(b * T + krow) * 1536 + 768 + h * 64 + (kcol >> 1);
    const unsigned short* pvBase = Vt + ((((size_t)b * 12 + h) * 64 + krow) << 11) + (kcol >> 1);

    const int ntA = qtA + 1, ntB = qtB + 1;

    // prologue: load tile 0 -> buf0; issue loads for tile 1
    s16x8 k0 = *(const s16x8*)(pkBase);
    s16x8 k1 = *(const s16x8*)(pkBase + 8);
    s16x8 v0 = *(const s16x8*)(pvBase);
    s16x8 v1 = *(const s16x8*)(pvBase + 8);
    *(s16x8*)(smem + swz128(krow, kcol)) = k0;
    *(s16x8*)(smem + swz128(krow, kcol + 16)) = k1;
    *(s16x8*)(smem + 16384 + swz128(krow, kcol)) = v0;
    *(s16x8*)(smem + 16384 + swz128(krow, kcol + 16)) = v1;
    if (ntB > 1) {
        const unsigned short* pk = pkBase + (size_t)64 * 1536;
        k0 = *(const s16x8*)(pk);
        k1 = *(const s16x8*)(pk + 8);
        const unsigned short* pv = pvBase + 64;
        v0 = *(const s16x8*)(pv);
        v1 = *(const s16x8*)(pv + 8);
    }
    BARRIER_LGKM();

    char* const pbaseB = smem + 32768 + wid * 2048;
    char* const pbaseA = smem + 40960 + wid * 2048;
    const int q_rel = wid * 16 + lr;

    for (int t = 0; t < ntB; t++) {
        char* kbase = smem + (t & 1) * 8192;
        char* vbase = smem + 16384 + (t & 1) * 8192;
        const bool actA = (t < ntA);

        // ---- phase 1: QK^T + exp + P-write for B, then A (separate buffers) ----
        {
            f32x4 st[4];
            __builtin_amdgcn_s_setprio(1);
#pragma unroll
            for (int nf = 0; nf < 4; nf++) {
                f32x4 sf = f32x4{0.f, 0.f, 0.f, 0.f};
#pragma unroll
                for (int ks = 0; ks < 2; ks++) {
                    s16x8 ak = *(const s16x8*)(kbase + swz128(nf * 16 + lr, (ks * 32 + g * 8) * 2));
                    sf = MFMA16x16x32(ak, aqB[ks], sf);
                }
                st[nf] = sf;
            }
            __builtin_amdgcn_s_setprio(0);
            const bool diag = (t == ntB - 1);
#pragma unroll
            for (int nf = 0; nf < 4; nf++)
#pragma unroll
                for (int rg = 0; rg < 4; rg++) {
                    float p = __builtin_amdgcn_exp2f(st[nf][rg]);
                    if (diag && (nf * 16 + g * 4 + rg > q_rel)) p = 0.f;
                    st[nf][rg] = p;
                }
#pragma unroll
            for (int nf = 0; nf < 4; nf++) {
                uint2 dw;
                dw.x = cvt_pk_bf2(st[nf][0], st[nf][1]);
                dw.y = cvt_pk_bf2(st[nf][2], st[nf][3]);
                *(uint2*)(pbaseB + swz128(lr, nf * 32 + g * 8)) = dw;
            }
        }
        if (actA) {
            f32x4 st[4];
            __builtin_amdgcn_s_setprio(1);
#pragma unroll
            for (int nf = 0; nf < 4; nf++) {
                f32x4 sf = f32x4{0.f, 0.f, 0.f, 0.f};
#pragma unroll
                for (int ks = 0; ks < 2; ks++) {
                    s16x8 ak = *(const s16x8*)(kbase + swz128(nf * 16 + lr, (ks * 32 + g * 8) * 2));
                    sf = MFMA16x16x32(ak, aqA[ks], sf);
                }
                st[nf] = sf;
            }
            __builtin_amdgcn_s_setprio(0);
            const bool diag = (t == ntA - 1);
#pragma unroll
            for (int nf = 0; nf < 4; nf++)
#pragma unroll
                for (int rg = 0; rg < 4; rg++) {
                    float p = __builtin_amdgcn_exp2f(st[nf][rg]);
                    if (diag && (nf * 16 + g * 4 + rg > q_rel)) p = 0.f;
                    st[nf][rg] = p;
                }
#pragma unroll
            for (int nf = 0; nf < 4; nf++) {
                uint2 dw;
                dw.x = cvt_pk_bf2(st[nf][0], st[nf][1]);
                dw.y = cvt_pk_bf2(st[nf][2], st[nf][3]);
                *(uint2*)(pbaseA + swz128(lr, nf * 32 + g * 8)) = dw;
            }
        }

        // ---- phase 2: P-read + PV + ones-MFMA row-sum for B, then A ----
        {
            s16x8 pf[2];
#pragma unroll
            for (int ks = 0; ks < 2; ks++)
                pf[ks] = *(const s16x8*)(pbaseB + swz128(lr, ks * 64 + g * 16));
            __builtin_amdgcn_s_setprio(1);
#pragma unroll
            for (int nf = 0; nf < 4; nf++) {
#pragma unroll
                for (int ks = 0; ks < 2; ks++) {
                    s16x8 bv = *(const s16x8*)(vbase + swz128(nf * 16 + lr, ks * 64 + g * 16));
                    oB[nf] = MFMA16x16x32(pf[ks], bv, oB[nf]);
                }
            }
            lsumB = MFMA16x16x32(pf[0], vone, lsumB);
            lsumB = MFMA16x16x32(pf[1], vone, lsumB);
            __builtin_amdgcn_s_setprio(0);
        }
        if (actA) {
            s16x8 pf[2];
#pragma unroll
            for (int ks = 0; ks < 2; ks++)
                pf[ks] = *(const s16x8*)(pbaseA + swz128(lr, ks * 64 + g * 16));
            __builtin_amdgcn_s_setprio(1);
#pragma unroll
            for (int nf = 0; nf < 4; nf++) {
#pragma unroll
                for (int ks = 0; ks < 2; ks++) {
                    s16x8 bv = *(const s16x8*)(vbase + swz128(nf * 16 + lr, ks * 64 + g * 16));
                    oA[nf] = MFMA16x16x32(pf[ks], bv, oA[nf]);
                }
            }
            lsumA = MFMA16x16x32(pf[0], vone, lsumA);
            lsumA = MFMA16x16x32(pf[1], vone, lsumA);
            __builtin_amdgcn_s_setprio(0);
        }

        // stage tile t+1 into the other buffer; issue loads for t+2
        if (t + 1 < ntB) {
            char* kn = smem + ((t + 1) & 1) * 8192;
            char* vn = smem + 16384 + ((t + 1) & 1) * 8192;
            *(s16x8*)(kn + swz128(krow, kcol)) = k0;
            *(s16x8*)(kn + swz128(krow, kcol + 16)) = k1;
            *(s16x8*)(vn + swz128(krow, kcol)) = v0;
            *(s16x8*)(vn + swz128(krow, kcol + 16)) = v1;
            if (t + 2 < ntB) {
                const unsigned short* pk = pkBase + (size_t)(t + 2) * 64 * 1536;
                k0 = *(const s16x8*)(pk);
                k1 = *(const s16x8*)(pk + 8);
                const unsigned short* pv = pvBase + (t + 2) * 64;
                v0 = *(const s16x8*)(pv);
                v1 = *(const s16x8*)(pv + 8);
            }
        }
        BARRIER_LGKM();              // single barrier per tile
    }

    // epilogue: lsum[rg] is the row-sum for q = wid*16+g*4+rg — same slot as o
#pragma unroll
    for (int which = 0; which < 2; which++) {
        const f32x4 lsum = which ? lsumB : lsumA;
        const int q0 = which ? q0B : q0A;
        f32x4* o = which ? oB : oA;
        float linv_q[4];
#pragma unroll
        for (int rg = 0; rg < 4; rg++) linv_q[rg] = 1.0f / lsum[rg];
#pragma unroll
        for (int nf = 0; nf < 4; nf++) {
#pragma unroll
            for (int rg = 0; rg < 4; rg++) {
                int row = b * T + q0 + wid * 16 + g * 4 + rg;
                int col = h * 64 + nf * 16 + lr;
                y[(size_t)row * 768 + col] = f2bf(o[nf][rg] * linv_q[rg]);
            }
        }
    }
}

extern "C" void kernel_launch(void* const* d_in, const int* in_sizes, int n_in,
                              void* d_out, int out_size, void* d_ws, size_t ws_size,
                              hipStream_t stream) {
    const float* x      = (const float*)d_in[0];
    const float* w_attn = (const float*)d_in[1];
    const float* b_attn = (const float*)d_in[2];
    const float* w_proj = (const float*)d_in[3];
    const float* b_proj = (const float*)d_in[4];

    char* ws = (char*)d_ws;
    unsigned short* qk  = (unsigned short*)(ws);
    unsigned short* Vt  = (unsigned short*)(ws + 25165824);
    unsigned short* wTa = (unsigned short*)(ws + 37748736);
    unsigned short* wTp = (unsigned short*)(ws + 41287680);

    const bool big = ws_size >= (size_t)55050240;
    unsigned short* xb = (unsigned short*)d_out;
    unsigned short* yb = big ? (unsigned short*)(ws + 42467328)
                             : (unsigned short*)((char*)d_out + 12582912);
    float* projOut = big ? (float*)d_out : (float*)ws;

    prologue_kernel<<<4352, 256, 0, stream>>>(x, xb, w_attn, wTa, w_proj, wTp);

    // qscale = 0.125 * log2(e): softmax scale and exp->exp2 folded into Q
    gemm_bt<true><<<1152, 256, 0, stream>>>(xb, wTa, b_attn, (void*)qk, Vt,
                                            8192, 2304, 768, 1536, 768, 0.1803368801111244f);
    attn_kernel<<<768, 256, 0, stream>>>(qk, Vt, yb);
    gemm_bt_half<<<768, 256, 0, stream>>>(yb, wTp, b_proj, projOut, 8192, 768, 768, 768);
    if (!big)
        hipMemcpyAsync(d_out, projOut, 25165824, hipMemcpyDeviceToDevice, stream);
}

// Round 21
// 116.171 us; speedup vs baseline: 1.3698x; 1.0060x over previous
//
#include <hip/hip_runtime.h>
#include <hip/hip_bf16.h>

using f32x4 = __attribute__((ext_vector_type(4))) float;
using s16x8 = __attribute__((ext_vector_type(8))) short;

#define MFMA16x16x32(a, b, c) __builtin_amdgcn_mfma_f32_16x16x32_bf16((a), (b), (c), 0, 0, 0)

#define AS_G(p) ((const __attribute__((address_space(1))) void*)(p))
#define AS_L(p) ((__attribute__((address_space(3))) void*)(p))

// barrier with LDS-visibility only: does NOT drain vmcnt
#define BARRIER_LGKM() do { \
    asm volatile("s_waitcnt lgkmcnt(0)" ::: "memory"); \
    __builtin_amdgcn_s_barrier(); \
} while (0)

static __device__ __forceinline__ unsigned short f2bf(float f) {
    unsigned int u = __float_as_uint(f);
    u = (u + 0x7fffu + ((u >> 16) & 1u)) >> 16;
    return (unsigned short)u;
}
static __device__ __forceinline__ unsigned int cvt_pk_bf2(float lo, float hi) {
    unsigned int r;
    asm("v_cvt_pk_bf16_f32 %0, %1, %2" : "=v"(r) : "v"(lo), "v"(hi));
    return r;
}
// swizzled byte offsets — used IDENTICALLY on write and read sides
static __device__ __forceinline__ int swz128(int r, int c) { return (r * 128 + c) ^ ((r & 7) << 4); }
static __device__ __forceinline__ int swz256v(int r, int c) { return (r * 256 + c) ^ ((r & 7) << 4); }

// ---- fused prologue: x->bf16 convert + both weight transposes ----
__global__ __launch_bounds__(256)
void prologue_kernel(const float* __restrict__ x, unsigned short* __restrict__ xb,
                     const float* __restrict__ w_attn, unsigned short* __restrict__ wTa,
                     const float* __restrict__ w_proj, unsigned short* __restrict__ wTp) {
    __shared__ float tile[32][33];
    const int bid = blockIdx.x, tid = threadIdx.x;
    if (bid < 2048) {
        const int n = 8192 * 768;
        int i = (bid * 256 + tid) * 4;
        const int stride = 2048 * 256 * 4;
        for (; i < n; i += stride) {
            float4 v = *(const float4*)(x + i);
            ushort4 o;
            o.x = f2bf(v.x); o.y = f2bf(v.y); o.z = f2bf(v.z); o.w = f2bf(v.w);
            *(ushort4*)(xb + i) = o;
        }
    } else {
        const float* w; unsigned short* wt; int K, N, bx, by;
        if (bid < 3776) {
            int id = bid - 2048; w = w_attn; wt = wTa; K = 768; N = 2304;
            bx = id % 72; by = id / 72;
        } else {
            int id = bid - 3776; w = w_proj; wt = wTp; K = 768; N = 768;
            bx = id % 24; by = id / 24;
        }
        const int tx = tid & 31, ty = tid >> 5;
        const int n0 = bx * 32, k0 = by * 32;
#pragma unroll
        for (int r = 0; r < 4; r++)
            tile[ty * 4 + r][tx] = w[(size_t)(k0 + ty * 4 + r) * N + n0 + tx];
        __syncthreads();
#pragma unroll
        for (int r = 0; r < 4; r++)
            wt[(size_t)(n0 + ty * 4 + r) * K + k0 + tx] = f2bf(tile[tx][ty * 4 + r]);
    }
}

// ---- GEMM: C[M,N] = A[M,K] * Bt[N,K]^T + bias (round-18 proven) ----
template <bool OUT_BF16>
__global__ __launch_bounds__(256, 2)
void gemm_bt(const unsigned short* __restrict__ A, const unsigned short* __restrict__ Bt,
             const float* __restrict__ bias, void* __restrict__ Cout,
             unsigned short* __restrict__ Vt,
             int M, int N, int K, int ldc, int qcols, float qscale) {
    __shared__ char smem[65536];
    const int tid = threadIdx.x, wid = tid >> 6, lane = tid & 63;
    const int g = lane >> 4, lr = lane & 15;
    const int nx = N >> 7;
    const int ypx = (M >> 7) >> 3;
    const int xcd = blockIdx.x & 7, ii = blockIdx.x >> 3;
    const int m0 = (xcd * ypx + ii / nx) * 128;
    const int n0 = (ii % nx) * 128;
    const int wm = wid >> 1, wn = wid & 1;

    f32x4 acc[4][4];
#pragma unroll
    for (int i = 0; i < 4; i++)
#pragma unroll
        for (int j = 0; j < 4; j++) acc[i][j] = f32x4{0.f, 0.f, 0.f, 0.f};

    const int rbase = lane >> 3;
    const int cSw = ((lane & 7) << 4) ^ (rbase << 4);

    auto STAGE = [&](int buf, int kt) {
        char* base = smem + buf * 32768;
#pragma unroll
        for (int ww = 0; ww < 4; ww++) {
            int w = wid * 4 + ww;
            int r = w * 8 + rbase;
            const unsigned short* srcA = A + (size_t)(m0 + r) * K + kt + (cSw >> 1);
            __builtin_amdgcn_global_load_lds(AS_G(srcA), AS_L(base + w * 1024), 16, 0, 0);
            const unsigned short* srcB = Bt + (size_t)(n0 + r) * K + kt + (cSw >> 1);
            __builtin_amdgcn_global_load_lds(AS_G(srcB), AS_L(base + 16384 + w * 1024), 16, 0, 0);
        }
    };

    const int nk = K >> 6;
    STAGE(0, 0);

    for (int t = 0; t < nk; t++) {
        if (t + 1 < nk) {
            STAGE((t + 1) & 1, (t + 1) << 6);
            asm volatile("s_waitcnt vmcnt(8)" ::: "memory");   // t's 8 loads done
        } else {
            asm volatile("s_waitcnt vmcnt(0)" ::: "memory");
        }
        __builtin_amdgcn_s_barrier();
        char* cbase = smem + (t & 1) * 32768;
#pragma unroll
        for (int ks = 0; ks < 2; ks++) {
            s16x8 af[4], bfr[4];
#pragma unroll
            for (int i = 0; i < 4; i++)
                af[i] = *(const s16x8*)(cbase + swz128(wm * 64 + i * 16 + lr, ks * 64 + g * 16));
#pragma unroll
            for (int j = 0; j < 4; j++)
                bfr[j] = *(const s16x8*)(cbase + 16384 + swz128(wn * 64 + j * 16 + lr, ks * 64 + g * 16));
#pragma unroll
            for (int i = 0; i < 4; i++)
#pragma unroll
                for (int j = 0; j < 4; j++)
                    acc[i][j] = MFMA16x16x32(af[i], bfr[j], acc[i][j]);
        }
        BARRIER_LGKM();
    }

    if (Vt != nullptr && n0 >= 1536) {
        // V block: bounce C-tile through LDS transposed, store coalesced.
#pragma unroll
        for (int j = 0; j < 4; j++) {
            int dl = wn * 64 + j * 16 + lr;
            float bv = bias[n0 + dl];
#pragma unroll
            for (int i = 0; i < 4; i++) {
                int tl = wm * 64 + i * 16 + g * 4;
                ushort4 o4;
                o4.x = f2bf(acc[i][j][0] + bv);
                o4.y = f2bf(acc[i][j][1] + bv);
                o4.z = f2bf(acc[i][j][2] + bv);
                o4.w = f2bf(acc[i][j][3] + bv);
                *(ushort4*)(smem + swz256v(dl, tl * 2)) = o4;
            }
        }
        __syncthreads();
        const int bb = m0 >> 11, t0 = m0 & 2047;
#pragma unroll
        for (int it = 0; it < 8; it++) {
            int dl = it * 16 + wid * 4 + g;
            int dg = (n0 - 1536) + dl;
            int hh = dg >> 6, dd = dg & 63;
            s16x8 v = *(const s16x8*)(smem + swz256v(dl, lr * 16));
            *(s16x8*)(Vt + ((((size_t)bb * 12 + hh) * 64 + dd) << 11) + t0 + lr * 8) = v;
        }
    } else {
#pragma unroll
        for (int j = 0; j < 4; j++) {
            int c = n0 + wn * 64 + j * 16 + lr;
            float bv = bias[c];
            float cscale = (c < qcols) ? qscale : 1.0f;
#pragma unroll
            for (int i = 0; i < 4; i++) {
#pragma unroll
                for (int rg = 0; rg < 4; rg++) {
                    int r = m0 + wm * 64 + i * 16 + g * 4 + rg;
                    float val = (acc[i][j][rg] + bv) * cscale;
                    if constexpr (OUT_BF16)
                        ((unsigned short*)Cout)[(size_t)r * ldc + c] = f2bf(val);
                    else
                        ((float*)Cout)[(size_t)r * ldc + c] = val;
                }
            }
        }
    }
}

// ---- proj GEMM, BM=64 variant (round-20) ----
__global__ __launch_bounds__(256, 3)
void gemm_bt_half(const unsigned short* __restrict__ A, const unsigned short* __restrict__ Bt,
                  const float* __restrict__ bias, float* __restrict__ Cout,
                  int M, int N, int K, int ldc) {
    __shared__ char smem[49152];
    const int tid = threadIdx.x, wid = tid >> 6, lane = tid & 63;
    const int g = lane >> 4, lr = lane & 15;
    const int nx = N >> 7;
    const int ypx = (M >> 6) >> 3;
    const int xcd = blockIdx.x & 7, ii = blockIdx.x >> 3;
    const int m0 = (xcd * ypx + ii / nx) * 64;
    const int n0 = (ii % nx) * 128;

    f32x4 acc[4][2];
#pragma unroll
    for (int i = 0; i < 4; i++)
#pragma unroll
        for (int j = 0; j < 2; j++) acc[i][j] = f32x4{0.f, 0.f, 0.f, 0.f};

    const int rbase = lane >> 3;
    const int cSw = ((lane & 7) << 4) ^ (rbase << 4);

    auto STAGE = [&](int buf, int kt) {
        char* base = smem + buf * 24576;
#pragma unroll
        for (int ww = 0; ww < 2; ww++) {
            int w = wid * 2 + ww;
            int r = w * 8 + rbase;
            const unsigned short* srcA = A + (size_t)(m0 + r) * K + kt + (cSw >> 1);
            __builtin_amdgcn_global_load_lds(AS_G(srcA), AS_L(base + w * 1024), 16, 0, 0);
        }
#pragma unroll
        for (int ww = 0; ww < 4; ww++) {
            int w = wid * 4 + ww;
            int r = w * 8 + rbase;
            const unsigned short* srcB = Bt + (size_t)(n0 + r) * K + kt + (cSw >> 1);
            __builtin_amdgcn_global_load_lds(AS_G(srcB), AS_L(base + 8192 + w * 1024), 16, 0, 0);
        }
    };

    const int nk = K >> 6;
    STAGE(0, 0);

    for (int t = 0; t < nk; t++) {
        if (t + 1 < nk) {
            STAGE((t + 1) & 1, (t + 1) << 6);
            asm volatile("s_waitcnt vmcnt(6)" ::: "memory");
        } else {
            asm volatile("s_waitcnt vmcnt(0)" ::: "memory");
        }
        __builtin_amdgcn_s_barrier();
        char* cbase = smem + (t & 1) * 24576;
#pragma unroll
        for (int ks = 0; ks < 2; ks++) {
            s16x8 af[4], bfr[2];
#pragma unroll
            for (int i = 0; i < 4; i++)
                af[i] = *(const s16x8*)(cbase + swz128(i * 16 + lr, ks * 64 + g * 16));
#pragma unroll
            for (int j = 0; j < 2; j++)
                bfr[j] = *(const s16x8*)(cbase + 8192 + swz128(wid * 32 + j * 16 + lr, ks * 64 + g * 16));
#pragma unroll
            for (int i = 0; i < 4; i++)
#pragma unroll
                for (int j = 0; j < 2; j++)
                    acc[i][j] = MFMA16x16x32(af[i], bfr[j], acc[i][j]);
        }
        BARRIER_LGKM();
    }

#pragma unroll
    for (int j = 0; j < 2; j++) {
        int c = n0 + wid * 32 + j * 16 + lr;
        float bv = bias[c];
#pragma unroll
        for (int i = 0; i < 4; i++) {
#pragma unroll
            for (int rg = 0; rg < 4; rg++) {
                int r = m0 + i * 16 + g * 4 + rg;
                Cout[(size_t)r * ldc + c] = acc[i][j][rg] + bv;
            }
        }
    }
}

// ---- causal flash attention: round-14 compute body + global_load_lds K/V
// staging (GEMM's proven pattern: linear LDS dest, pre-inverse-swizzled
// source; K and V LDS rows are 128B so swz128's XOR is self-contained).
// Per tile: vmcnt(0) [own stage loads landed] -> barrier -> issue STAGE(t+1)
// (full tile to land) -> compute. Removes the reg round-trip (4 glob loads +
// 4 ds_writes + 16 VGPRs) and the in-body vmcnt coupling.
__global__ __launch_bounds__(256, 2)
void attn_kernel(const unsigned short* __restrict__ qk, const unsigned short* __restrict__ Vt,
                 unsigned short* __restrict__ y) {
    __shared__ char smem[49152];
    const int tid = threadIdx.x, wid = tid >> 6, lane = tid & 63;
    const int g = lane >> 4, lr = lane & 15;
    const int T = 2048;

    const int s = blockIdx.x;
    const int xcd = s & 7, i = s >> 3;
    const int grp = xcd * 6 + (i >> 4);
    const int qpi = i & 15;
    const int h = grp % 12, b = grp / 12;
    const int qtA = qpi, qtB = 31 - qpi;
    const int q0A = qtA * 64, q0B = qtB * 64;

    s16x8 vone;
#pragma unroll
    for (int e = 0; e < 8; e++) vone[e] = (short)0x3F80;   // bf16 1.0

    const unsigned short* qrowA = qk + (size_t)(b * T + q0A + wid * 16 + lr) * 1536 + h * 64;
    const unsigned short* qrowB = qk + (size_t)(b * T + q0B + wid * 16 + lr) * 1536 + h * 64;
    s16x8 aqA[2], aqB[2];
    aqA[0] = *(const s16x8*)(qrowA + g * 8);
    aqA[1] = *(const s16x8*)(qrowA + 32 + g * 8);
    aqB[0] = *(const s16x8*)(qrowB + g * 8);
    aqB[1] = *(const s16x8*)(qrowB + 32 + g * 8);

    f32x4 oA[4], oB[4], lsumA, lsumB;
#pragma unroll
    for (int r = 0; r < 4; r++) { oA[r] = f32x4{0.f, 0.f, 0.f, 0.f}; oB[r] = f32x4{0.f, 0.f, 0.f, 0.f}; }
    lsumA = f32x4{0.f, 0.f, 0.f, 0.f};
    lsumB = f32x4{0.f, 0.f, 0.f, 0.f};

    // staging geometry: window w (1KB) covers 8 rows; this lane covers
    // row w*8 + (lane>>3), pre-swizzled col byte cSw (GEMM pattern).
    const int rbase = lane >> 3;
    const int cSw = ((lane & 7) << 4) ^ (rbase << 4);
    const unsigned short* pkBase = qk + (size_t)(b * T) * 1536 + 768 + h * 64 + (cSw >> 1);
    const unsigned short* pvBase = Vt + (((size_t)b * 12 + h) << 17) + (cSw >> 1);

    // per wave: 2 K windows (wid*2+ww) + 2 V windows
    auto STAGE = [&](int buf, int j0) {
        char* kb = smem + buf * 8192;
        char* vb = smem + 16384 + buf * 8192;
#pragma unroll
        for (int ww = 0; ww < 2; ww++) {
            int w = wid * 2 + ww;
            int jj = w * 8 + rbase;
            const unsigned short* srcK = pkBase + (size_t)(j0 + jj) * 1536;
            __builtin_amdgcn_global_load_lds(AS_G(srcK), AS_L(kb + w * 1024), 16, 0, 0);
            const unsigned short* srcV = pvBase + ((size_t)jj << 11) + j0;
            __builtin_amdgcn_global_load_lds(AS_G(srcV), AS_L(vb + w * 1024), 16, 0, 0);
        }
    };

    const int ntA = qtA + 1, ntB = qtB + 1;

    STAGE(0, 0);   // tile 0 in flight

    char* const pbaseB = smem + 32768 + wid * 2048;
    char* const pbaseA = smem + 40960 + wid * 2048;
    const int q_rel = wid * 16 + lr;

    for (int t = 0; t < ntB; t++) {
        asm volatile("s_waitcnt vmcnt(0)" ::: "memory");  // own STAGE(t) landed
        BARRIER_LGKM();                                   // all waves' stage visible
        if (t + 1 < ntB) STAGE((t + 1) & 1, (t + 1) * 64);

        char* kbase = smem + (t & 1) * 8192;
        char* vbase = smem + 16384 + (t & 1) * 8192;
        const bool actA = (t < ntA);

        // ---- phase 1: QK^T + exp + P-write for B, then A (separate buffers) ----
        {
            f32x4 st[4];
            __builtin_amdgcn_s_setprio(1);
#pragma unroll
            for (int nf = 0; nf < 4; nf++) {
                f32x4 sf = f32x4{0.f, 0.f, 0.f, 0.f};
#pragma unroll
                for (int ks = 0; ks < 2; ks++) {
                    s16x8 ak = *(const s16x8*)(kbase + swz128(nf * 16 + lr, (ks * 32 + g * 8) * 2));
                    sf = MFMA16x16x32(ak, aqB[ks], sf);
                }
                st[nf] = sf;
            }
            __builtin_amdgcn_s_setprio(0);
            const bool diag = (t == ntB - 1);
#pragma unroll
            for (int nf = 0; nf < 4; nf++)
#pragma unroll
                for (int rg = 0; rg < 4; rg++) {
                    float p = __builtin_amdgcn_exp2f(st[nf][rg]);
                    if (diag && (nf * 16 + g * 4 + rg > q_rel)) p = 0.f;
                    st[nf][rg] = p;
                }
#pragma unroll
            for (int nf = 0; nf < 4; nf++) {
                uint2 dw;
                dw.x = cvt_pk_bf2(st[nf][0], st[nf][1]);
                dw.y = cvt_pk_bf2(st[nf][2], st[nf][3]);
                *(uint2*)(pbaseB + swz128(lr, nf * 32 + g * 8)) = dw;
            }
        }
        if (actA) {
            f32x4 st[4];
            __builtin_amdgcn_s_setprio(1);
#pragma unroll
            for (int nf = 0; nf < 4; nf++) {
                f32x4 sf = f32x4{0.f, 0.f, 0.f, 0.f};
#pragma unroll
                for (int ks = 0; ks < 2; ks++) {
                    s16x8 ak = *(const s16x8*)(kbase + swz128(nf * 16 + lr, (ks * 32 + g * 8) * 2));
                    sf = MFMA16x16x32(ak, aqA[ks], sf);
                }
                st[nf] = sf;
            }
            __builtin_amdgcn_s_setprio(0);
            const bool diag = (t == ntA - 1);
#pragma unroll
            for (int nf = 0; nf < 4; nf++)
#pragma unroll
                for (int rg = 0; rg < 4; rg++) {
                    float p = __builtin_amdgcn_exp2f(st[nf][rg]);
                    if (diag && (nf * 16 + g * 4 + rg > q_rel)) p = 0.f;
                    st[nf][rg] = p;
                }
#pragma unroll
            for (int nf = 0; nf < 4; nf++) {
                uint2 dw;
                dw.x = cvt_pk_bf2(st[nf][0], st[nf][1]);
                dw.y = cvt_pk_bf2(st[nf][2], st[nf][3]);
                *(uint2*)(pbaseA + swz128(lr, nf * 32 + g * 8)) = dw;
            }
        }

        // ---- phase 2: P-read + PV + ones-MFMA row-sum for B, then A ----
        {
            s16x8 pf[2];
#pragma unroll
            for (int ks = 0; ks < 2; ks++)
                pf[ks] = *(const s16x8*)(pbaseB + swz128(lr, ks * 64 + g * 16));
            __builtin_amdgcn_s_setprio(1);
#pragma unroll
            for (int nf = 0; nf < 4; nf++) {
#pragma unroll
                for (int ks = 0; ks < 2; ks++) {
                    s16x8 bv = *(const s16x8*)(vbase + swz128(nf * 16 + lr, ks * 64 + g * 16));
                    oB[nf] = MFMA16x16x32(pf[ks], bv, oB[nf]);
                }
            }
            lsumB = MFMA16x16x32(pf[0], vone, lsumB);
            lsumB = MFMA16x16x32(pf[1], vone, lsumB);
            __builtin_amdgcn_s_setprio(0);
        }
        if (actA) {
            s16x8 pf[2];
#pragma unroll
            for (int ks = 0; ks < 2; ks++)
                pf[ks] = *(const s16x8*)(pbaseA + swz128(lr, ks * 64 + g * 16));
            __builtin_amdgcn_s_setprio(1);
#pragma unroll
            for (int nf = 0; nf < 4; nf++) {
#pragma unroll
                for (int ks = 0; ks < 2; ks++) {
                    s16x8 bv = *(const s16x8*)(vbase + swz128(nf * 16 + lr, ks * 64 + g * 16));
                    oA[nf] = MFMA16x16x32(pf[ks], bv, oA[nf]);
                }
            }
            lsumA = MFMA16x16x32(pf[0], vone, lsumA);
            lsumA = MFMA16x16x32(pf[1], vone, lsumA);
            __builtin_amdgcn_s_setprio(0);
        }
    }

    // epilogue: lsum[rg] is the row-sum for q = wid*16+g*4+rg — same slot as o
#pragma unroll
    for (int which = 0; which < 2; which++) {
        const f32x4 lsum = which ? lsumB : lsumA;
        const int q0 = which ? q0B : q0A;
        f32x4* o = which ? oB : oA;
        float linv_q[4];
#pragma unroll
        for (int rg = 0; rg < 4; rg++) linv_q[rg] = 1.0f / lsum[rg];
#pragma unroll
        for (int nf = 0; nf < 4; nf++) {
#pragma unroll
            for (int rg = 0; rg < 4; rg++) {
                int row = b * T + q0 + wid * 16 + g * 4 + rg;
                int col = h * 64 + nf * 16 + lr;
                y[(size_t)row * 768 + col] = f2bf(o[nf][rg] * linv_q[rg]);
            }
        }
    }
}

extern "C" void kernel_launch(void* const* d_in, const int* in_sizes, int n_in,
                              void* d_out, int out_size, void* d_ws, size_t ws_size,
                              hipStream_t stream) {
    const float* x      = (const float*)d_in[0];
    const float* w_attn = (const float*)d_in[1];
    const float* b_attn = (const float*)d_in[2];
    const float* w_proj = (const float*)d_in[3];
    const float* b_proj = (const float*)d_in[4];

    char* ws = (char*)d_ws;
    unsigned short* qk  = (unsigned short*)(ws);
    unsigned short* Vt  = (unsigned short*)(ws + 25165824);
    unsigned short* wTa = (unsigned short*)(ws + 37748736);
    unsigned short* wTp = (unsigned short*)(ws + 41287680);

    const bool big = ws_size >= (size_t)55050240;
    unsigned short* xb = (unsigned short*)d_out;
    unsigned short* yb = big ? (unsigned short*)(ws + 42467328)
                             : (unsigned short*)((char*)d_out + 12582912);
    float* projOut = big ? (float*)d_out : (float*)ws;

    prologue_kernel<<<4352, 256, 0, stream>>>(x, xb, w_attn, wTa, w_proj, wTp);

    // qscale = 0.125 * log2(e): softmax scale and exp->exp2 folded into Q
    gemm_bt<true><<<1152, 256, 0, stream>>>(xb, wTa, b_attn, (void*)qk, Vt,
                                            8192, 2304, 768, 1536, 768, 0.1803368801111244f);
    attn_kernel<<<768, 256, 0, stream>>>(qk, Vt, yb);
    gemm_bt_half<<<768, 256, 0, stream>>>(yb, wTp, b_proj, projOut, 8192, 768, 768, 768);
    if (!big)
        hipMemcpyAsync(d_out, projOut, 25165824, hipMemcpyDeviceToDevice, stream);
}

// Round 22
// 115.400 us; speedup vs baseline: 1.3790x; 1.0067x over previous
//
#include <hip/hip_runtime.h>
#include <hip/hip_bf16.h>

using f32x4 = __attribute__((ext_vector_type(4))) float;
using s16x8 = __attribute__((ext_vector_type(8))) short;

#define MFMA16x16x32(a, b, c) __builtin_amdgcn_mfma_f32_16x16x32_bf16((a), (b), (c), 0, 0, 0)

#define AS_G(p) ((const __attribute__((address_space(1))) void*)(p))
#define AS_L(p) ((__attribute__((address_space(3))) void*)(p))

// barrier with LDS-visibility only: does NOT drain vmcnt
#define BARRIER_LGKM() do { \
    asm volatile("s_waitcnt lgkmcnt(0)" ::: "memory"); \
    __builtin_amdgcn_s_barrier(); \
} while (0)

static __device__ __forceinline__ unsigned short f2bf(float f) {
    unsigned int u = __float_as_uint(f);
    u = (u + 0x7fffu + ((u >> 16) & 1u)) >> 16;
    return (unsigned short)u;
}
static __device__ __forceinline__ unsigned int cvt_pk_bf2(float lo, float hi) {
    unsigned int r;
    asm("v_cvt_pk_bf16_f32 %0, %1, %2" : "=v"(r) : "v"(lo), "v"(hi));
    return r;
}
// swizzled byte offset — used IDENTICALLY on write and read sides
static __device__ __forceinline__ int swz128(int r, int c) { return (r * 128 + c) ^ ((r & 7) << 4); }

// ---- fused prologue: x->bf16 convert + both weight transposes ----
__global__ __launch_bounds__(256)
void prologue_kernel(const float* __restrict__ x, unsigned short* __restrict__ xb,
                     const float* __restrict__ w_attn, unsigned short* __restrict__ wTa,
                     const float* __restrict__ w_proj, unsigned short* __restrict__ wTp) {
    __shared__ float tile[32][33];
    const int bid = blockIdx.x, tid = threadIdx.x;
    if (bid < 2048) {
        const int n = 8192 * 768;
        int i = (bid * 256 + tid) * 4;
        const int stride = 2048 * 256 * 4;
        for (; i < n; i += stride) {
            float4 v = *(const float4*)(x + i);
            ushort4 o;
            o.x = f2bf(v.x); o.y = f2bf(v.y); o.z = f2bf(v.z); o.w = f2bf(v.w);
            *(ushort4*)(xb + i) = o;
        }
    } else {
        const float* w; unsigned short* wt; int K, N, bx, by;
        if (bid < 3776) {
            int id = bid - 2048; w = w_attn; wt = wTa; K = 768; N = 2304;
            bx = id % 72; by = id / 72;
        } else {
            int id = bid - 3776; w = w_proj; wt = wTp; K = 768; N = 768;
            bx = id % 24; by = id / 24;
        }
        const int tx = tid & 31, ty = tid >> 5;
        const int n0 = bx * 32, k0 = by * 32;
#pragma unroll
        for (int r = 0; r < 4; r++)
            tile[ty * 4 + r][tx] = w[(size_t)(k0 + ty * 4 + r) * N + n0 + tx];
        __syncthreads();
#pragma unroll
        for (int r = 0; r < 4; r++)
            wt[(size_t)(n0 + ty * 4 + r) * K + k0 + tx] = f2bf(tile[tx][ty * 4 + r]);
    }
}

// ---- GEMM, BM=64 x BN=128 (proj-proven structure, round 20/21): grid
// (M/64)*(N/128), XCD-clustered; LDS 2 x (A 8K + B 16K) = 48KB -> 3 blocks/CU
// (12 waves/CU vs 8 for the BM=128 variant -> better stall hiding + exact
// 3-round grid balance). Counted vmcnt(6). Epilogues: bf16/f32 C with
// optional qscale on c<qcols; V-region blocks (n0>=1536) bounce the 64x128
// tile through LDS transposed [128 d][64 t] and store Vt 16B-coalesced.
template <bool OUT_BF16>
__global__ __launch_bounds__(256, 3)
void gemm_bt64(const unsigned short* __restrict__ A, const unsigned short* __restrict__ Bt,
               const float* __restrict__ bias, void* __restrict__ Cout,
               unsigned short* __restrict__ Vt,
               int M, int N, int K, int ldc, int qcols, float qscale) {
    __shared__ char smem[49152];
    const int tid = threadIdx.x, wid = tid >> 6, lane = tid & 63;
    const int g = lane >> 4, lr = lane & 15;
    const int nx = N >> 7;
    const int ypx = (M >> 6) >> 3;           // 64-row panels per XCD
    const int xcd = blockIdx.x & 7, ii = blockIdx.x >> 3;
    const int m0 = (xcd * ypx + ii / nx) * 64;
    const int n0 = (ii % nx) * 128;

    f32x4 acc[4][2];
#pragma unroll
    for (int i = 0; i < 4; i++)
#pragma unroll
        for (int j = 0; j < 2; j++) acc[i][j] = f32x4{0.f, 0.f, 0.f, 0.f};

    const int rbase = lane >> 3;
    const int cSw = ((lane & 7) << 4) ^ (rbase << 4);

    auto STAGE = [&](int buf, int kt) {
        char* base = smem + buf * 24576;
#pragma unroll
        for (int ww = 0; ww < 2; ww++) {
            int w = wid * 2 + ww;            // 0..7  (A: 64 rows)
            int r = w * 8 + rbase;
            const unsigned short* srcA = A + (size_t)(m0 + r) * K + kt + (cSw >> 1);
            __builtin_amdgcn_global_load_lds(AS_G(srcA), AS_L(base + w * 1024), 16, 0, 0);
        }
#pragma unroll
        for (int ww = 0; ww < 4; ww++) {
            int w = wid * 4 + ww;            // 0..15 (B: 128 rows)
            int r = w * 8 + rbase;
            const unsigned short* srcB = Bt + (size_t)(n0 + r) * K + kt + (cSw >> 1);
            __builtin_amdgcn_global_load_lds(AS_G(srcB), AS_L(base + 8192 + w * 1024), 16, 0, 0);
        }
    };

    const int nk = K >> 6;
    STAGE(0, 0);

    for (int t = 0; t < nk; t++) {
        if (t + 1 < nk) {
            STAGE((t + 1) & 1, (t + 1) << 6);
            asm volatile("s_waitcnt vmcnt(6)" ::: "memory");   // t's 6 loads done
        } else {
            asm volatile("s_waitcnt vmcnt(0)" ::: "memory");
        }
        __builtin_amdgcn_s_barrier();
        char* cbase = smem + (t & 1) * 24576;
#pragma unroll
        for (int ks = 0; ks < 2; ks++) {
            s16x8 af[4], bfr[2];
#pragma unroll
            for (int i = 0; i < 4; i++)
                af[i] = *(const s16x8*)(cbase + swz128(i * 16 + lr, ks * 64 + g * 16));
#pragma unroll
            for (int j = 0; j < 2; j++)
                bfr[j] = *(const s16x8*)(cbase + 8192 + swz128(wid * 32 + j * 16 + lr, ks * 64 + g * 16));
#pragma unroll
            for (int i = 0; i < 4; i++)
#pragma unroll
                for (int j = 0; j < 2; j++)
                    acc[i][j] = MFMA16x16x32(af[i], bfr[j], acc[i][j]);
        }
        BARRIER_LGKM();
    }

    if (Vt != nullptr && n0 >= 1536) {
        // V block: bounce 64x128 C-tile through LDS transposed [128 d][64 t]
        // (128B rows, swz128), then store 16B-coalesced into Vt[b][h][d][t].
#pragma unroll
        for (int j = 0; j < 2; j++) {
            int dl = wid * 32 + j * 16 + lr;        // d-local 0..127
            float bv = bias[n0 + dl];
#pragma unroll
            for (int i = 0; i < 4; i++) {
                int tl = i * 16 + g * 4;            // t-local 0..63
                ushort4 o4;
                o4.x = f2bf(acc[i][j][0] + bv);
                o4.y = f2bf(acc[i][j][1] + bv);
                o4.z = f2bf(acc[i][j][2] + bv);
                o4.w = f2bf(acc[i][j][3] + bv);
                *(ushort4*)(smem + swz128(dl, tl * 2)) = o4;
            }
        }
        __syncthreads();
        const int bb = m0 >> 11, t0 = m0 & 2047;
#pragma unroll
        for (int it = 0; it < 4; it++) {
            int dl = it * 32 + (tid >> 3);
            int dg = (n0 - 1536) + dl;
            int hh = dg >> 6, dd = dg & 63;
            s16x8 v = *(const s16x8*)(smem + swz128(dl, (tid & 7) * 16));
            *(s16x8*)(Vt + ((((size_t)bb * 12 + hh) * 64 + dd) << 11) + t0 + (tid & 7) * 8) = v;
        }
    } else {
#pragma unroll
        for (int j = 0; j < 2; j++) {
            int c = n0 + wid * 32 + j * 16 + lr;
            float bv = bias[c];
            float cscale = (c < qcols) ? qscale : 1.0f;
#pragma unroll
            for (int i = 0; i < 4; i++) {
#pragma unroll
                for (int rg = 0; rg < 4; rg++) {
                    int r = m0 + i * 16 + g * 4 + rg;
                    float val = (acc[i][j][rg] + bv) * cscale;
                    if constexpr (OUT_BF16)
                        ((unsigned short*)Cout)[(size_t)r * ldc + c] = f2bf(val);
                    else
                        ((float*)Cout)[(size_t)r * ldc + c] = val;
                }
            }
        }
    }
}

// ---- causal flash attention: round-21 proven (48.5 us) ----
__global__ __launch_bounds__(256, 2)
void attn_kernel(const unsigned short* __restrict__ qk, const unsigned short* __restrict__ Vt,
                 unsigned short* __restrict__ y) {
    __shared__ char smem[49152];
    const int tid = threadIdx.x, wid = tid >> 6, lane = tid & 63;
    const int g = lane >> 4, lr = lane & 15;
    const int T = 2048;

    const int s = blockIdx.x;
    const int xcd = s & 7, i = s >> 3;
    const int grp = xcd * 6 + (i >> 4);
    const int qpi = i & 15;
    const int h = grp % 12, b = grp / 12;
    const int qtA = qpi, qtB = 31 - qpi;
    const int q0A = qtA * 64, q0B = qtB * 64;

    s16x8 vone;
#pragma unroll
    for (int e = 0; e < 8; e++) vone[e] = (short)0x3F80;   // bf16 1.0

    const unsigned short* qrowA = qk + (size_t)(b * T + q0A + wid * 16 + lr) * 1536 + h * 64;
    const unsigned short* qrowB = qk + (size_t)(b * T + q0B + wid * 16 + lr) * 1536 + h * 64;
    s16x8 aqA[2], aqB[2];
    aqA[0] = *(const s16x8*)(qrowA + g * 8);
    aqA[1] = *(const s16x8*)(qrowA + 32 + g * 8);
    aqB[0] = *(const s16x8*)(qrowB + g * 8);
    aqB[1] = *(const s16x8*)(qrowB + 32 + g * 8);

    f32x4 oA[4], oB[4], lsumA, lsumB;
#pragma unroll
    for (int r = 0; r < 4; r++) { oA[r] = f32x4{0.f, 0.f, 0.f, 0.f}; oB[r] = f32x4{0.f, 0.f, 0.f, 0.f}; }
    lsumA = f32x4{0.f, 0.f, 0.f, 0.f};
    lsumB = f32x4{0.f, 0.f, 0.f, 0.f};

    const int rbase = lane >> 3;
    const int cSw = ((lane & 7) << 4) ^ (rbase << 4);
    const unsigned short* pkBase = qk + (size_t)(b * T) * 1536 + 768 + h * 64 + (cSw >> 1);
    const unsigned short* pvBase = Vt + (((size_t)b * 12 + h) << 17) + (cSw >> 1);

    auto STAGE = [&](int buf, int j0) {
        char* kb = smem + buf * 8192;
        char* vb = smem + 16384 + buf * 8192;
#pragma unroll
        for (int ww = 0; ww < 2; ww++) {
            int w = wid * 2 + ww;
            int jj = w * 8 + rbase;
            const unsigned short* srcK = pkBase + (size_t)(j0 + jj) * 1536;
            __builtin_amdgcn_global_load_lds(AS_G(srcK), AS_L(kb + w * 1024), 16, 0, 0);
            const unsigned short* srcV = pvBase + ((size_t)jj << 11) + j0;
            __builtin_amdgcn_global_load_lds(AS_G(srcV), AS_L(vb + w * 1024), 16, 0, 0);
        }
    };

    const int ntA = qtA + 1, ntB = qtB + 1;

    STAGE(0, 0);   // tile 0 in flight

    char* const pbaseB = smem + 32768 + wid * 2048;
    char* const pbaseA = smem + 40960 + wid * 2048;
    const int q_rel = wid * 16 + lr;

    for (int t = 0; t < ntB; t++) {
        asm volatile("s_waitcnt vmcnt(0)" ::: "memory");  // own STAGE(t) landed
        BARRIER_LGKM();                                   // all waves' stage visible
        if (t + 1 < ntB) STAGE((t + 1) & 1, (t + 1) * 64);

        char* kbase = smem + (t & 1) * 8192;
        char* vbase = smem + 16384 + (t & 1) * 8192;
        const bool actA = (t < ntA);

        // ---- phase 1: QK^T + exp + P-write for B, then A (separate buffers) ----
        {
            f32x4 st[4];
            __builtin_amdgcn_s_setprio(1);
#pragma unroll
            for (int nf = 0; nf < 4; nf++) {
                f32x4 sf = f32x4{0.f, 0.f, 0.f, 0.f};
#pragma unroll
                for (int ks = 0; ks < 2; ks++) {
                    s16x8 ak = *(const s16x8*)(kbase + swz128(nf * 16 + lr, (ks * 32 + g * 8) * 2));
                    sf = MFMA16x16x32(ak, aqB[ks], sf);
                }
                st[nf] = sf;
            }
            __builtin_amdgcn_s_setprio(0);
            const bool diag = (t == ntB - 1);
#pragma unroll
            for (int nf = 0; nf < 4; nf++)
#pragma unroll
                for (int rg = 0; rg < 4; rg++) {
                    float p = __builtin_amdgcn_exp2f(st[nf][rg]);
                    if (diag && (nf * 16 + g * 4 + rg > q_rel)) p = 0.f;
                    st[nf][rg] = p;
                }
#pragma unroll
            for (int nf = 0; nf < 4; nf++) {
                uint2 dw;
                dw.x = cvt_pk_bf2(st[nf][0], st[nf][1]);
                dw.y = cvt_pk_bf2(st[nf][2], st[nf][3]);
                *(uint2*)(pbaseB + swz128(lr, nf * 32 + g * 8)) = dw;
            }
        }
        if (actA) {
            f32x4 st[4];
            __builtin_amdgcn_s_setprio(1);
#pragma unroll
            for (int nf = 0; nf < 4; nf++) {
                f32x4 sf = f32x4{0.f, 0.f, 0.f, 0.f};
#pragma unroll
                for (int ks = 0; ks < 2; ks++) {
                    s16x8 ak = *(const s16x8*)(kbase + swz128(nf * 16 + lr, (ks * 32 + g * 8) * 2));
                    sf = MFMA16x16x32(ak, aqA[ks], sf);
                }
                st[nf] = sf;
            }
            __builtin_amdgcn_s_setprio(0);
            const bool diag = (t == ntA - 1);
#pragma unroll
            for (int nf = 0; nf < 4; nf++)
#pragma unroll
                for (int rg = 0; rg < 4; rg++) {
                    float p = __builtin_amdgcn_exp2f(st[nf][rg]);
                    if (diag && (nf * 16 + g * 4 + rg > q_rel)) p = 0.f;
                    st[nf][rg] = p;
                }
#pragma unroll
            for (int nf = 0; nf < 4; nf++) {
                uint2 dw;
                dw.x = cvt_pk_bf2(st[nf][0], st[nf][1]);
                dw.y = cvt_pk_bf2(st[nf][2], st[nf][3]);
                *(uint2*)(pbaseA + swz128(lr, nf * 32 + g * 8)) = dw;
            }
        }

        // ---- phase 2: P-read + PV + ones-MFMA row-sum for B, then A ----
        {
            s16x8 pf[2];
#pragma unroll
            for (int ks = 0; ks < 2; ks++)
                pf[ks] = *(const s16x8*)(pbaseB + swz128(lr, ks * 64 + g * 16));
            __builtin_amdgcn_s_setprio(1);
#pragma unroll
            for (int nf = 0; nf < 4; nf++) {
#pragma unroll
                for (int ks = 0; ks < 2; ks++) {
                    s16x8 bv = *(const s16x8*)(vbase + swz128(nf * 16 + lr, ks * 64 + g * 16));
                    oB[nf] = MFMA16x16x32(pf[ks], bv, oB[nf]);
                }
            }
            lsumB = MFMA16x16x32(pf[0], vone, lsumB);
            lsumB = MFMA16x16x32(pf[1], vone, lsumB);
            __builtin_amdgcn_s_setprio(0);
        }
        if (actA) {
            s16x8 pf[2];
#pragma unroll
            for (int ks = 0; ks < 2; ks++)
                pf[ks] = *(const s16x8*)(pbaseA + swz128(lr, ks * 64 + g * 16));
            __builtin_amdgcn_s_setprio(1);
#pragma unroll
            for (int nf = 0; nf < 4; nf++) {
#pragma unroll
                for (int ks = 0; ks < 2; ks++) {
                    s16x8 bv = *(const s16x8*)(vbase + swz128(nf * 16 + lr, ks * 64 + g * 16));
                    oA[nf] = MFMA16x16x32(pf[ks], bv, oA[nf]);
                }
            }
            lsumA = MFMA16x16x32(pf[0], vone, lsumA);
            lsumA = MFMA16x16x32(pf[1], vone, lsumA);
            __builtin_amdgcn_s_setprio(0);
        }
    }

    // epilogue: lsum[rg] is the row-sum for q = wid*16+g*4+rg — same slot as o
#pragma unroll
    for (int which = 0; which < 2; which++) {
        const f32x4 lsum = which ? lsumB : lsumA;
        const int q0 = which ? q0B : q0A;
        f32x4* o = which ? oB : oA;
        float linv_q[4];
#pragma unroll
        for (int rg = 0; rg < 4; rg++) linv_q[rg] = 1.0f / lsum[rg];
#pragma unroll
        for (int nf = 0; nf < 4; nf++) {
#pragma unroll
            for (int rg = 0; rg < 4; rg++) {
                int row = b * T + q0 + wid * 16 + g * 4 + rg;
                int col = h * 64 + nf * 16 + lr;
                y[(size_t)row * 768 + col] = f2bf(o[nf][rg] * linv_q[rg]);
            }
        }
    }
}

extern "C" void kernel_launch(void* const* d_in, const int* in_sizes, int n_in,
                              void* d_out, int out_size, void* d_ws, size_t ws_size,
                              hipStream_t stream) {
    const float* x      = (const float*)d_in[0];
    const float* w_attn = (const float*)d_in[1];
    const float* b_attn = (const float*)d_in[2];
    const float* w_proj = (const float*)d_in[3];
    const float* b_proj = (const float*)d_in[4];

    char* ws = (char*)d_ws;
    unsigned short* qk  = (unsigned short*)(ws);
    unsigned short* Vt  = (unsigned short*)(ws + 25165824);
    unsigned short* wTa = (unsigned short*)(ws + 37748736);
    unsigned short* wTp = (unsigned short*)(ws + 41287680);

    const bool big = ws_size >= (size_t)55050240;
    unsigned short* xb = (unsigned short*)d_out;
    unsigned short* yb = big ? (unsigned short*)(ws + 42467328)
                             : (unsigned short*)((char*)d_out + 12582912);
    float* projOut = big ? (float*)d_out : (float*)ws;

    prologue_kernel<<<4352, 256, 0, stream>>>(x, xb, w_attn, wTa, w_proj, wTp);

    // qscale = 0.125 * log2(e): softmax scale and exp->exp2 folded into Q
    gemm_bt64<true><<<2304, 256, 0, stream>>>(xb, wTa, b_attn, (void*)qk, Vt,
                                              8192, 2304, 768, 1536, 768, 0.1803368801111244f);
    attn_kernel<<<768, 256, 0, stream>>>(qk, Vt, yb);
    gemm_bt64<false><<<768, 256, 0, stream>>>(yb, wTp, b_proj, (void*)projOut, nullptr,
                                              8192, 768, 768, 768, 0, 1.0f);
    if (!big)
        hipMemcpyAsync(d_out, projOut, 25165824, hipMemcpyDeviceToDevice, stream);
}

// Round 23
// 114.818 us; speedup vs baseline: 1.3860x; 1.0051x over previous
//
#include <hip/hip_runtime.h>
#include <hip/hip_bf16.h>

using f32x4 = __attribute__((ext_vector_type(4))) float;
using s16x8 = __attribute__((ext_vector_type(8))) short;

#define MFMA16x16x32(a, b, c) __builtin_amdgcn_mfma_f32_16x16x32_bf16((a), (b), (c), 0, 0, 0)

#define AS_G(p) ((const __attribute__((address_space(1))) void*)(p))
#define AS_L(p) ((__attribute__((address_space(3))) void*)(p))

static __device__ __forceinline__ unsigned short f2bf(float f) {
    unsigned int u = __float_as_uint(f);
    u = (u + 0x7fffu + ((u >> 16) & 1u)) >> 16;
    return (unsigned short)u;
}
static __device__ __forceinline__ unsigned int cvt_pk_bf2(float lo, float hi) {
    unsigned int r;
    asm("v_cvt_pk_bf16_f32 %0, %1, %2" : "=v"(r) : "v"(lo), "v"(hi));
    return r;
}
// swizzled byte offset — used IDENTICALLY on write and read sides
static __device__ __forceinline__ int swz128(int r, int c) { return (r * 128 + c) ^ ((r & 7) << 4); }

// ---- fused prologue: x->bf16 convert + both weight transposes ----
__global__ __launch_bounds__(256)
void prologue_kernel(const float* __restrict__ x, unsigned short* __restrict__ xb,
                     const float* __restrict__ w_attn, unsigned short* __restrict__ wTa,
                     const float* __restrict__ w_proj, unsigned short* __restrict__ wTp) {
    __shared__ float tile[32][33];
    const int bid = blockIdx.x, tid = threadIdx.x;
    if (bid < 2048) {
        const int n = 8192 * 768;
        int i = (bid * 256 + tid) * 4;
        const int stride = 2048 * 256 * 4;
        for (; i < n; i += stride) {
            float4 v = *(const float4*)(x + i);
            ushort4 o;
            o.x = f2bf(v.x); o.y = f2bf(v.y); o.z = f2bf(v.z); o.w = f2bf(v.w);
            *(ushort4*)(xb + i) = o;
        }
    } else {
        const float* w; unsigned short* wt; int K, N, bx, by;
        if (bid < 3776) {
            int id = bid - 2048; w = w_attn; wt = wTa; K = 768; N = 2304;
            bx = id % 72; by = id / 72;
        } else {
            int id = bid - 3776; w = w_proj; wt = wTp; K = 768; N = 768;
            bx = id % 24; by = id / 24;
        }
        const int tx = tid & 31, ty = tid >> 5;
        const int n0 = bx * 32, k0 = by * 32;
#pragma unroll
        for (int r = 0; r < 4; r++)
            tile[ty * 4 + r][tx] = w[(size_t)(k0 + ty * 4 + r) * N + n0 + tx];
        __syncthreads();
#pragma unroll
        for (int r = 0; r < 4; r++)
            wt[(size_t)(n0 + ty * 4 + r) * K + k0 + tx] = f2bf(tile[tx][ty * 4 + r]);
    }
}

// ---- GEMM, BM=64 x BN=128 (round-22 structure; plain s_barrier — lgkm
// drain was redundant: staging is vmcnt-domain gload_lds, ds_read results
// consumed before the barrier) ----
template <bool OUT_BF16>
__global__ __launch_bounds__(256, 3)
void gemm_bt64(const unsigned short* __restrict__ A, const unsigned short* __restrict__ Bt,
               const float* __restrict__ bias, void* __restrict__ Cout,
               unsigned short* __restrict__ Vt,
               int M, int N, int K, int ldc, int qcols, float qscale) {
    __shared__ char smem[49152];
    const int tid = threadIdx.x, wid = tid >> 6, lane = tid & 63;
    const int g = lane >> 4, lr = lane & 15;
    const int nx = N >> 7;
    const int ypx = (M >> 6) >> 3;           // 64-row panels per XCD
    const int xcd = blockIdx.x & 7, ii = blockIdx.x >> 3;
    const int m0 = (xcd * ypx + ii / nx) * 64;
    const int n0 = (ii % nx) * 128;

    f32x4 acc[4][2];
#pragma unroll
    for (int i = 0; i < 4; i++)
#pragma unroll
        for (int j = 0; j < 2; j++) acc[i][j] = f32x4{0.f, 0.f, 0.f, 0.f};

    const int rbase = lane >> 3;
    const int cSw = ((lane & 7) << 4) ^ (rbase << 4);

    auto STAGE = [&](int buf, int kt) {
        char* base = smem + buf * 24576;
#pragma unroll
        for (int ww = 0; ww < 2; ww++) {
            int w = wid * 2 + ww;            // A: 64 rows
            int r = w * 8 + rbase;
            const unsigned short* srcA = A + (size_t)(m0 + r) * K + kt + (cSw >> 1);
            __builtin_amdgcn_global_load_lds(AS_G(srcA), AS_L(base + w * 1024), 16, 0, 0);
        }
#pragma unroll
        for (int ww = 0; ww < 4; ww++) {
            int w = wid * 4 + ww;            // B: 128 rows
            int r = w * 8 + rbase;
            const unsigned short* srcB = Bt + (size_t)(n0 + r) * K + kt + (cSw >> 1);
            __builtin_amdgcn_global_load_lds(AS_G(srcB), AS_L(base + 8192 + w * 1024), 16, 0, 0);
        }
    };

    const int nk = K >> 6;
    STAGE(0, 0);

    for (int t = 0; t < nk; t++) {
        if (t + 1 < nk) {
            STAGE((t + 1) & 1, (t + 1) << 6);
            asm volatile("s_waitcnt vmcnt(6)" ::: "memory");   // t's 6 loads done
        } else {
            asm volatile("s_waitcnt vmcnt(0)" ::: "memory");
        }
        __builtin_amdgcn_s_barrier();
        char* cbase = smem + (t & 1) * 24576;
#pragma unroll
        for (int ks = 0; ks < 2; ks++) {
            s16x8 af[4], bfr[2];
#pragma unroll
            for (int i = 0; i < 4; i++)
                af[i] = *(const s16x8*)(cbase + swz128(i * 16 + lr, ks * 64 + g * 16));
#pragma unroll
            for (int j = 0; j < 2; j++)
                bfr[j] = *(const s16x8*)(cbase + 8192 + swz128(wid * 32 + j * 16 + lr, ks * 64 + g * 16));
#pragma unroll
            for (int i = 0; i < 4; i++)
#pragma unroll
                for (int j = 0; j < 2; j++)
                    acc[i][j] = MFMA16x16x32(af[i], bfr[j], acc[i][j]);
        }
        __builtin_amdgcn_s_barrier();   // readers of buf[t&1] done before t+2 lands
    }

    if (Vt != nullptr && n0 >= 1536) {
        // V block: bounce 64x128 C-tile through LDS transposed [128 d][64 t],
        // store 16B-coalesced into Vt[b][h][d][t].
#pragma unroll
        for (int j = 0; j < 2; j++) {
            int dl = wid * 32 + j * 16 + lr;
            float bv = bias[n0 + dl];
#pragma unroll
            for (int i = 0; i < 4; i++) {
                int tl = i * 16 + g * 4;
                ushort4 o4;
                o4.x = f2bf(acc[i][j][0] + bv);
                o4.y = f2bf(acc[i][j][1] + bv);
                o4.z = f2bf(acc[i][j][2] + bv);
                o4.w = f2bf(acc[i][j][3] + bv);
                *(ushort4*)(smem + swz128(dl, tl * 2)) = o4;
            }
        }
        __syncthreads();
        const int bb = m0 >> 11, t0 = m0 & 2047;
#pragma unroll
        for (int it = 0; it < 4; it++) {
            int dl = it * 32 + (tid >> 3);
            int dg = (n0 - 1536) + dl;
            int hh = dg >> 6, dd = dg & 63;
            s16x8 v = *(const s16x8*)(smem + swz128(dl, (tid & 7) * 16));
            *(s16x8*)(Vt + ((((size_t)bb * 12 + hh) * 64 + dd) << 11) + t0 + (tid & 7) * 8) = v;
        }
    } else {
#pragma unroll
        for (int j = 0; j < 2; j++) {
            int c = n0 + wid * 32 + j * 16 + lr;
            float bv = bias[c];
            float cscale = (c < qcols) ? qscale : 1.0f;
#pragma unroll
            for (int i = 0; i < 4; i++) {
#pragma unroll
                for (int rg = 0; rg < 4; rg++) {
                    int r = m0 + i * 16 + g * 4 + rg;
                    float val = (acc[i][j][rg] + bv) * cscale;
                    if constexpr (OUT_BF16)
                        ((unsigned short*)Cout)[(size_t)r * ldc + c] = f2bf(val);
                    else
                        ((float*)Cout)[(size_t)r * ldc + c] = val;
                }
            }
        }
    }
}

// ---- causal flash attention: SEQUENTIAL pair sweeps (r12 skeleton) with all
// proven upgrades: every block does exactly 33 rounds AND 33 compute units
// (uniform round shape across blocks -> no CU tail skew, unlike the merged
// sweep's 17..32-round spread). gload_lds K/V staging, single P buffer
// (LDS 40KB), ones-MFMA lsum, exp2-folded Q, XCD-clustered pair grid.
__global__ __launch_bounds__(256, 2)
void attn_kernel(const unsigned short* __restrict__ qk, const unsigned short* __restrict__ Vt,
                 unsigned short* __restrict__ y) {
    __shared__ char smem[40960]; // K dbuf [0,16K) | V dbuf [16K,32K) | P 4x2K [32K,40K)
    const int tid = threadIdx.x, wid = tid >> 6, lane = tid & 63;
    const int g = lane >> 4, lr = lane & 15;
    const int T = 2048;

    const int s = blockIdx.x;
    const int xcd = s & 7, i = s >> 3;
    const int grp = xcd * 6 + (i >> 4);
    const int qpi = i & 15;
    const int h = grp % 12, b = grp / 12;

    s16x8 vone;
#pragma unroll
    for (int e = 0; e < 8; e++) vone[e] = (short)0x3F80;   // bf16 1.0

    const int rbase = lane >> 3;
    const int cSw = ((lane & 7) << 4) ^ (rbase << 4);
    const unsigned short* pkBase = qk + (size_t)(b * T) * 1536 + 768 + h * 64 + (cSw >> 1);
    const unsigned short* pvBase = Vt + (((size_t)b * 12 + h) << 17) + (cSw >> 1);

    auto STAGE = [&](int buf, int j0) {
        char* kb = smem + buf * 8192;
        char* vb = smem + 16384 + buf * 8192;
#pragma unroll
        for (int ww = 0; ww < 2; ww++) {
            int w = wid * 2 + ww;
            int jj = w * 8 + rbase;
            const unsigned short* srcK = pkBase + (size_t)(j0 + jj) * 1536;
            __builtin_amdgcn_global_load_lds(AS_G(srcK), AS_L(kb + w * 1024), 16, 0, 0);
            const unsigned short* srcV = pvBase + ((size_t)jj << 11) + j0;
            __builtin_amdgcn_global_load_lds(AS_G(srcV), AS_L(vb + w * 1024), 16, 0, 0);
        }
    };

    char* const pbase = smem + 32768 + wid * 2048;
    const int q_rel = wid * 16 + lr;

    for (int pp = 0; pp < 2; pp++) {
        const int qt = pp ? (31 - qpi) : qpi;
        const int q0 = qt * 64;
        const int nt = qt + 1;

        const unsigned short* qrow = qk + (size_t)(b * T + q0 + wid * 16 + lr) * 1536 + h * 64;
        s16x8 aq[2];
        aq[0] = *(const s16x8*)(qrow + g * 8);
        aq[1] = *(const s16x8*)(qrow + 32 + g * 8);

        f32x4 o[4], lsum;
#pragma unroll
        for (int r = 0; r < 4; r++) o[r] = f32x4{0.f, 0.f, 0.f, 0.f};
        lsum = f32x4{0.f, 0.f, 0.f, 0.f};

        if (pp) __builtin_amdgcn_s_barrier();   // prior sweep's buf readers done
        STAGE(0, 0);

        for (int t = 0; t < nt; t++) {
            asm volatile("s_waitcnt vmcnt(0)" ::: "memory");  // own STAGE(t) landed
            __builtin_amdgcn_s_barrier();                     // all waves' stage visible
            if (t + 1 < nt) STAGE((t + 1) & 1, (t + 1) * 64);

            char* kbase = smem + (t & 1) * 8192;
            char* vbase = smem + 16384 + (t & 1) * 8192;

            // phase 1: S'^T = K Q^T (Q pre-scaled by 0.125*log2e)
            f32x4 st[4];
            __builtin_amdgcn_s_setprio(1);
#pragma unroll
            for (int nf = 0; nf < 4; nf++) {
                f32x4 sf = f32x4{0.f, 0.f, 0.f, 0.f};
#pragma unroll
                for (int ks = 0; ks < 2; ks++) {
                    s16x8 ak = *(const s16x8*)(kbase + swz128(nf * 16 + lr, (ks * 32 + g * 8) * 2));
                    sf = MFMA16x16x32(ak, aq[ks], sf);
                }
                st[nf] = sf;
            }
            __builtin_amdgcn_s_setprio(0);

            const bool diag = (t == nt - 1);
#pragma unroll
            for (int nf = 0; nf < 4; nf++)
#pragma unroll
                for (int rg = 0; rg < 4; rg++) {
                    float p = __builtin_amdgcn_exp2f(st[nf][rg]);
                    if (diag && (nf * 16 + g * 4 + rg > q_rel)) p = 0.f;
                    st[nf][rg] = p;
                }
#pragma unroll
            for (int nf = 0; nf < 4; nf++) {
                uint2 dw;
                dw.x = cvt_pk_bf2(st[nf][0], st[nf][1]);
                dw.y = cvt_pk_bf2(st[nf][2], st[nf][3]);
                *(uint2*)(pbase + swz128(lr, nf * 32 + g * 8)) = dw;
            }

            // phase 2: P-read + PV + ones-MFMA row-sum
            s16x8 pf[2];
#pragma unroll
            for (int ks = 0; ks < 2; ks++)
                pf[ks] = *(const s16x8*)(pbase + swz128(lr, ks * 64 + g * 16));
            __builtin_amdgcn_s_setprio(1);
#pragma unroll
            for (int nf = 0; nf < 4; nf++) {
#pragma unroll
                for (int ks = 0; ks < 2; ks++) {
                    s16x8 bv = *(const s16x8*)(vbase + swz128(nf * 16 + lr, ks * 64 + g * 16));
                    o[nf] = MFMA16x16x32(pf[ks], bv, o[nf]);
                }
            }
            lsum = MFMA16x16x32(pf[0], vone, lsum);
            lsum = MFMA16x16x32(pf[1], vone, lsum);
            __builtin_amdgcn_s_setprio(0);
        }

        // epilogue: lsum[rg] is the row-sum for q = wid*16+g*4+rg (same slot as o)
        float linv_q[4];
#pragma unroll
        for (int rg = 0; rg < 4; rg++) linv_q[rg] = 1.0f / lsum[rg];
#pragma unroll
        for (int nf = 0; nf < 4; nf++) {
#pragma unroll
            for (int rg = 0; rg < 4; rg++) {
                int row = b * T + q0 + wid * 16 + g * 4 + rg;
                int col = h * 64 + nf * 16 + lr;
                y[(size_t)row * 768 + col] = f2bf(o[nf][rg] * linv_q[rg]);
            }
        }
    }
}

extern "C" void kernel_launch(void* const* d_in, const int* in_sizes, int n_in,
                              void* d_out, int out_size, void* d_ws, size_t ws_size,
                              hipStream_t stream) {
    const float* x      = (const float*)d_in[0];
    const float* w_attn = (const float*)d_in[1];
    const float* b_attn = (const float*)d_in[2];
    const float* w_proj = (const float*)d_in[3];
    const float* b_proj = (const float*)d_in[4];

    char* ws = (char*)d_ws;
    unsigned short* qk  = (unsigned short*)(ws);
    unsigned short* Vt  = (unsigned short*)(ws + 25165824);
    unsigned short* wTa = (unsigned short*)(ws + 37748736);
    unsigned short* wTp = (unsigned short*)(ws + 41287680);

    const bool big = ws_size >= (size_t)55050240;
    unsigned short* xb = (unsigned short*)d_out;
    unsigned short* yb = big ? (unsigned short*)(ws + 42467328)
                             : (unsigned short*)((char*)d_out + 12582912);
    float* projOut = big ? (float*)d_out : (float*)ws;

    prologue_kernel<<<4352, 256, 0, stream>>>(x, xb, w_attn, wTa, w_proj, wTp);

    // qscale = 0.125 * log2(e): softmax scale and exp->exp2 folded into Q
    gemm_bt64<true><<<2304, 256, 0, stream>>>(xb, wTa, b_attn, (void*)qk, Vt,
                                              8192, 2304, 768, 1536, 768, 0.1803368801111244f);
    attn_kernel<<<768, 256, 0, stream>>>(qk, Vt, yb);
    gemm_bt64<false><<<768, 256, 0, stream>>>(yb, wTp, b_proj, (void*)projOut, nullptr,
                                              8192, 768, 768, 768, 0, 1.0f);
    if (!big)
        hipMemcpyAsync(d_out, projOut, 25165824, hipMemcpyDeviceToDevice, stream);
}